// Round 7
// baseline (313.980 us; speedup 1.0000x reference)
//
#include <hip/hip_runtime.h>
#include <hip/hip_bf16.h>
#include <math.h>

// Problem constants
#define B_  4
#define L_  512
#define H_  1024
#define M_  128
#define E_  64
#define NH_ 16
#define R_  1024
#define D_  768
#define BLK_ 64
#define C_  97
#define NROW (B_*R_)          // 4096
#define KB_  (D_/BLK_)        // 12

typedef __attribute__((ext_vector_type(8))) unsigned short ushort8;
typedef __attribute__((ext_vector_type(4))) unsigned short ushort4v;
typedef __attribute__((ext_vector_type(8))) short s8;       // 8 bf16 MFMA operand
typedef __attribute__((ext_vector_type(4))) float f4;       // MFMA C/D

__device__ __forceinline__ unsigned short f2bf(float x) {   // RNE f32->bf16
    unsigned u = __builtin_bit_cast(unsigned, x);
    unsigned r = (u + 0x7fffu + ((u >> 16) & 1u)) >> 16;
    return (unsigned short)r;
}
__device__ __forceinline__ float bf2f(unsigned short h) {
    unsigned u = ((unsigned)h) << 16;
    return __builtin_bit_cast(float, u);
}
__device__ __forceinline__ float lo16f(unsigned u) { return __builtin_bit_cast(float, u << 16); }
__device__ __forceinline__ float hi16f(unsigned u) { return __builtin_bit_cast(float, u & 0xffff0000u); }

// async global->LDS 16B (compiler never auto-emits; m97 lever). LDS dest
// semantics: wave-uniform base + lane*16 — callers must pass lane-linear lds.
__device__ __forceinline__ void gload_lds16(const unsigned short* g, unsigned short* l)
{
    __builtin_amdgcn_global_load_lds(
        (const __attribute__((address_space(1))) unsigned int*)g,
        (__attribute__((address_space(3))) unsigned int*)l, 16, 0, 0);
}

// ===========================================================================
// Stage 1a: entity logsumexp pooling -> bf16 (R9-verified)
// ===========================================================================
__global__ __launch_bounds__(256) void pool_lse(
    const float* __restrict__ ent_lhs, const int* __restrict__ labels,
    unsigned short* __restrict__ ent_embB)
{
    int be = blockIdx.x, b = be >> 6, e = be & 63;
    __shared__ int midx[M_];
    __shared__ int scnt;
    if (threadIdx.x == 0) scnt = 0;
    __syncthreads();
    if (threadIdx.x < M_) {
        if (labels[b*M_ + threadIdx.x] == e) {
            int p = atomicAdd(&scnt, 1);
            midx[p] = threadIdx.x;
        }
    }
    __syncthreads();
    int cnt = scnt;
    for (int h = threadIdx.x; h < H_; h += blockDim.x) {
        float r = 0.f;
        if (cnt > 0) {
            const float* base = ent_lhs + (size_t)b*M_*H_ + h;
            float mx = -INFINITY;
            for (int k = 0; k < cnt; ++k) mx = fmaxf(mx, base[(size_t)midx[k]*H_]);
            float s = 0.f;
            for (int k = 0; k < cnt; ++k) s += expf(base[(size_t)midx[k]*H_] - mx);
            r = mx + logf(s);
        }
        ent_embB[(size_t)be*H_ + h] = f2bf(r);
    }
}

// ===========================================================================
// Stage 1b: entity attention mean -> bf16. grid (E, B*NH)  (R9-verified)
// ===========================================================================
__global__ __launch_bounds__(256) void pool_attn(
    const float* __restrict__ attn, const int* __restrict__ labels,
    unsigned short* __restrict__ ent_attnB)
{
    int e  = blockIdx.x;
    int y  = blockIdx.y;          // b*NH + nh
    int b  = y >> 4, nh = y & 15;
    __shared__ int midx[M_];
    __shared__ int scnt;
    if (threadIdx.x == 0) scnt = 0;
    __syncthreads();
    if (threadIdx.x < M_) {
        if (labels[b*M_ + threadIdx.x] == e) {
            int p = atomicAdd(&scnt, 1);
            midx[p] = threadIdx.x;
        }
    }
    __syncthreads();
    int cnt = scnt;
    float inv = (cnt > 0) ? 1.f/(float)cnt : 0.f;
    const float* base = attn + ((size_t)(b*NH_ + nh)*M_)*L_;
    #pragma unroll
    for (int q = 0; q < 2; ++q) {
        int l = threadIdx.x + q*256;
        float s = 0.f;
        for (int k = 0; k < cnt; ++k) s += base[(size_t)midx[k]*L_ + l];
        ent_attnB[((size_t)(b*E_ + e)*NH_ + nh)*L_ + l] = f2bf(s * inv);
    }
}

// ===========================================================================
// Stage 2: pair attention bf16 in -> bf16 htA (R8-verified)
// ===========================================================================
__global__ __launch_bounds__(256) void pair_attn_kernel(
    const unsigned short* __restrict__ entA, const int* __restrict__ hts,
    unsigned short* __restrict__ htA)
{
    int br = blockIdx.x, b = br >> 10;
    int hi = hts[br*2 + 0], ti = hts[br*2 + 1];
    const unsigned* ph = (const unsigned*)(entA + ((size_t)(b*E_ + hi)*NH_)*L_);
    const unsigned* pt = (const unsigned*)(entA + ((size_t)(b*E_ + ti)*NH_)*L_);
    int l2 = threadIdx.x;                 // u32 index = pair of adjacent l's
    float v0 = 0.f, v1 = 0.f;
    #pragma unroll
    for (int nh = 0; nh < NH_; ++nh) {
        unsigned a = ph[nh*(L_/2) + l2], c = pt[nh*(L_/2) + l2];
        v0 += lo16f(a)*lo16f(c);
        v1 += hi16f(a)*hi16f(c);
    }
    float part = v0 + v1;
    __shared__ float red[4];
    #pragma unroll
    for (int off = 32; off > 0; off >>= 1) part += __shfl_down(part, off, 64);
    if ((threadIdx.x & 63) == 0) red[threadIdx.x >> 6] = part;
    __syncthreads();
    float total = red[0] + red[1] + red[2] + red[3];
    float norm = 1.f / (total*(1.f/16.f) + 1e-5f);   // denom on sum of nh-means
    unsigned short o0 = f2bf(v0*(1.f/16.f)*norm);
    unsigned short o1 = f2bf(v1*(1.f/16.f)*norm);
    *(unsigned*)(htA + (size_t)br*L_ + l2*2) = ((unsigned)o1 << 16) | o0;
}

// ===========================================================================
// Preps (R8-verified)
// ===========================================================================
__global__ __launch_bounds__(256) void transpose_cvt_seq(const float* __restrict__ in,
                                                         unsigned short* __restrict__ outp)
{
    int b = blockIdx.z;
    int h0 = blockIdx.x*32, l0 = blockIdx.y*32;
    __shared__ float tile[32][33];
    int tx = threadIdx.x & 31, ty = threadIdx.x >> 5;
    #pragma unroll
    for (int p = 0; p < 4; ++p)
        tile[ty + p*8][tx] = in[((size_t)b*L_ + l0 + ty + p*8)*H_ + h0 + tx];
    __syncthreads();
    #pragma unroll
    for (int p = 0; p < 4; ++p)
        outp[((size_t)b*H_ + h0 + ty + p*8)*L_ + l0 + tx] = f2bf(tile[tx][ty + p*8]);
}

__global__ __launch_bounds__(256) void transpose_cvt_W(const float* __restrict__ Wh,
                                                       const float* __restrict__ Wt,
                                                       unsigned short* __restrict__ WhT,
                                                       unsigned short* __restrict__ WtT)
{
    const float* in = blockIdx.z ? Wt : Wh;
    unsigned short* outp = blockIdx.z ? WtT : WhT;
    int n0 = blockIdx.x*32, k0 = blockIdx.y*32;
    __shared__ float tile[32][33];
    int tx = threadIdx.x & 31, ty = threadIdx.x >> 5;
    #pragma unroll
    for (int p = 0; p < 4; ++p)
        tile[ty + p*8][tx] = in[((size_t)(k0 + ty + p*8))*D_ + n0 + tx];
    __syncthreads();
    #pragma unroll
    for (int p = 0; p < 4; ++p) {
        int n = n0 + ty + p*8;
        outp[(size_t)n*2048 + k0 + tx] = f2bf(tile[tx][ty + p*8]);
    }
}

// gather ent rows (bf16 copy) into Ah/At cols [0,1024)  (R8-verified)
__global__ __launch_bounds__(256) void prep_gather(const unsigned short* __restrict__ entE,
                                                   const int* __restrict__ hts,
                                                   unsigned short* __restrict__ Ah,
                                                   unsigned short* __restrict__ At)
{
    int n = blockIdx.x, b = n >> 10;
    int m = threadIdx.x >> 7, off = (threadIdx.x & 127)*8;
    int idx = hts[n*2 + m];
    const unsigned short* src = entE + (size_t)(b*E_ + idx)*H_ + off;
    unsigned short* dst = (m ? At : Ah) + (size_t)n*2048 + off;
    *(ushort8*)dst = *(const ushort8*)src;
}

// WbT layout (R14): fragment-packed DENSE per wave-instruction.
// Element (i, c=wc*64+ct*16+lm, j=j2*32+quad*8+t) stored at
//   [kb][i][wc][ct][j2][quad][lm][t]
__global__ __launch_bounds__(256) void prep_WbT(const float* __restrict__ Wb,
                                                unsigned short* __restrict__ outp)
{
    int blk = blockIdx.x;                 // kb*64 + i
    __shared__ float sW[64*97];
    const float* src = Wb + (size_t)blk*64*97;
    for (int e = threadIdx.x; e < 64*97; e += 256) sW[e] = src[e];
    __syncthreads();
    unsigned short* dst = outp + (size_t)blk*128*64;
    for (int e = threadIdx.x; e < 128*64; e += 256) {
        int wcq = e >> 12;            // wc
        int ct  = (e >> 10) & 3;
        int j2  = (e >> 9) & 1;
        int qd  = (e >> 7) & 3;
        int lm  = (e >> 3) & 15;
        int t   = e & 7;
        int c   = wcq*64 + ct*16 + lm;
        int j   = j2*32 + qd*8 + t;   // k-index pairing preserved (R8 algebra)
        dst[e] = (c < C_) ? f2bf(sW[j*97 + c]) : (unsigned short)0;
    }
}

// ===========================================================================
// bf16 MFMA GEMM core — R15-verified: async global_load_lds staging.
// As/Bs UNPADDED [128][32] so lds_byte = ch*16 is lane-linear (m173).
// ===========================================================================
__device__ __forceinline__ void gemm128_core(const unsigned short* __restrict__ A,
                                             const unsigned short* __restrict__ Bt,
                                             int K, int row0, int col0,
                                             f4 (&acc)[4][4])
{
    __shared__ __attribute__((aligned(16))) unsigned short As[128][32];
    __shared__ __attribute__((aligned(16))) unsigned short Bs[128][32];
    int tid = threadIdx.x;
    int wave = tid >> 6, lane = tid & 63;
    int wr = wave & 1, wc = wave >> 1;
    int lm = lane & 15, quad = lane >> 4;

    for (int k0 = 0; k0 < K; k0 += 32) {
        #pragma unroll
        for (int s = 0; s < 2; ++s) {
            int ch = tid + s*256;
            int row = ch >> 2, part = ch & 3;     // lds_byte = ch*16 (lane-linear)
            gload_lds16(A  + (size_t)(row0 + row)*K + k0 + part*8, &As[0][0] + ch*8);
            gload_lds16(Bt + (size_t)(col0 + row)*K + k0 + part*8, &Bs[0][0] + ch*8);
        }
        __syncthreads();   // compiler drains vmcnt(0) before s_barrier
        s8 a[4], b[4];
        #pragma unroll
        for (int ti = 0; ti < 4; ++ti) a[ti] = *(const s8*)&As[wr*64 + ti*16 + lm][quad*8];
        #pragma unroll
        for (int tj = 0; tj < 4; ++tj) b[tj] = *(const s8*)&Bs[wc*64 + tj*16 + lm][quad*8];
        #pragma unroll
        for (int ti = 0; ti < 4; ++ti)
            #pragma unroll
            for (int tj = 0; tj < 4; ++tj)
                acc[ti][tj] = __builtin_amdgcn_mfma_f32_16x16x32_bf16(a[ti], b[tj], acc[ti][tj], 0, 0, 0);
        __syncthreads();
    }
}

// ===========================================================================
// Stage 3: rel GEMM -> bf16 into Ah/At cols [1024,2048)  (R8-verified)
// ===========================================================================
__global__ __launch_bounds__(256) void gemm_rel_mfma(const unsigned short* __restrict__ htA,
                                                     const unsigned short* __restrict__ seqT,
                                                     unsigned short* __restrict__ Ah,
                                                     unsigned short* __restrict__ At)
{
    int z = blockIdx.z;
    const unsigned short* A  = htA  + (size_t)z*R_*L_;
    const unsigned short* Bt = seqT + (size_t)z*H_*L_;
    int row0 = blockIdx.y*128, col0 = blockIdx.x*128;
    f4 acc[4][4] = {};
    gemm128_core(A, Bt, L_, row0, col0, acc);
    int lane = threadIdx.x & 63, wave = threadIdx.x >> 6;
    int wr = wave & 1, wc = wave >> 1, lm = lane & 15, quad = lane >> 4;
    #pragma unroll
    for (int ti = 0; ti < 4; ++ti)
        #pragma unroll
        for (int tj = 0; tj < 4; ++tj)
            #pragma unroll
            for (int r = 0; r < 4; ++r) {
                int n   = z*R_ + row0 + wr*64 + ti*16 + quad*4 + r;
                int col = col0 + wc*64 + tj*16 + lm;
                unsigned short v = f2bf(acc[ti][tj][r]);
                Ah[(size_t)n*2048 + 1024 + col] = v;
                At[(size_t)n*2048 + 1024 + col] = v;
            }
}

// ===========================================================================
// Stage 4: extractor GEMM (K=2048) + bias + tanh -> f32 hv/tv
// ===========================================================================
__global__ __launch_bounds__(256) void gemm_ext_mfma(
    const unsigned short* __restrict__ Ah, const unsigned short* __restrict__ At,
    const unsigned short* __restrict__ WhT, const unsigned short* __restrict__ WtT,
    const float* __restrict__ bh, const float* __restrict__ bt,
    float* __restrict__ hv, float* __restrict__ tv)
{
    int z = blockIdx.z;
    const unsigned short* A  = z ? At  : Ah;
    const unsigned short* Bt = z ? WtT : WhT;
    const float* bias = z ? bt : bh;
    float* C = z ? tv : hv;
    int row0 = blockIdx.y*128, col0 = blockIdx.x*128;
    f4 acc[4][4] = {};
    gemm128_core(A, Bt, 2048, row0, col0, acc);
    int lane = threadIdx.x & 63, wave = threadIdx.x >> 6;
    int wr = wave & 1, wc = wave >> 1, lm = lane & 15, quad = lane >> 4;
    #pragma unroll
    for (int ti = 0; ti < 4; ++ti)
        #pragma unroll
        for (int tj = 0; tj < 4; ++tj)
            #pragma unroll
            for (int r = 0; r < 4; ++r) {
                int row = row0 + wr*64 + ti*16 + quad*4 + r;
                int col = col0 + wc*64 + tj*16 + lm;
                float x = acc[ti][tj][r] + bias[col];
                float e = __expf(2.f*x);
                C[(size_t)row*D_ + col] = 1.f - 2.f/(e + 1.f);   // tanh
            }
}

// ===========================================================================
// Stage 5a: init output with bias
// ===========================================================================
__global__ void out_init(const float* __restrict__ bb, float* __restrict__ out)
{
    int i = blockIdx.x*256 + threadIdx.x;
    if (i < NROW*C_) out[i] = bb[i % C_];
}

// ===========================================================================
// Stage 5b helpers (R14-verified): direct-L2 B-frag load + one-i compute.
// ===========================================================================
__device__ __forceinline__ void loadB_frag(const unsigned short* __restrict__ bbase,
                                           int i, s8 (&dst)[4][2])
{
    #pragma unroll
    for (int ct = 0; ct < 4; ++ct) {
        dst[ct][0] = *(const s8*)(bbase + (size_t)i*8192 + ct*1024);
        dst[ct][1] = *(const s8*)(bbase + (size_t)i*8192 + ct*1024 + 512);
    }
}

__device__ __forceinline__ void compute_i(const s8 (&bfr)[4][2],
                                          float sh0, float sh1,
                                          const float (&tvv)[2][2][8],
                                          f4 (&acc)[2][4])
{
    // A-frags: bf16-truncate(hv_i * tv) packed via v_perm (R9-verified path)
    s8 afr0[2], afr1[2];
    #pragma unroll
    for (int j2 = 0; j2 < 2; ++j2) {
        union { unsigned u[4]; s8 v; } c0, c1;
        #pragma unroll
        for (int t2 = 0; t2 < 4; ++t2) {
            float pe0 = sh0 * tvv[0][j2][t2*2];
            float po0 = sh0 * tvv[0][j2][t2*2 + 1];
            float pe1 = sh1 * tvv[1][j2][t2*2];
            float po1 = sh1 * tvv[1][j2][t2*2 + 1];
            c0.u[t2] = __builtin_amdgcn_perm(__builtin_bit_cast(unsigned, po0),
                                             __builtin_bit_cast(unsigned, pe0),
                                             0x07060302u);
            c1.u[t2] = __builtin_amdgcn_perm(__builtin_bit_cast(unsigned, po1),
                                             __builtin_bit_cast(unsigned, pe1),
                                             0x07060302u);
        }
        afr0[j2] = c0.v; afr1[j2] = c1.v;
    }
    #pragma unroll
    for (int ct = 0; ct < 4; ++ct) {
        acc[0][ct] = __builtin_amdgcn_mfma_f32_16x16x32_bf16(afr0[0], bfr[ct][0], acc[0][ct], 0, 0, 0);
        acc[0][ct] = __builtin_amdgcn_mfma_f32_16x16x32_bf16(afr0[1], bfr[ct][1], acc[0][ct], 0, 0, 0);
        acc[1][ct] = __builtin_amdgcn_mfma_f32_16x16x32_bf16(afr1[0], bfr[ct][0], acc[1][ct], 0, 0, 0);
        acc[1][ct] = __builtin_amdgcn_mfma_f32_16x16x32_bf16(afr1[1], bfr[ct][1], acc[1][ct], 0, 0, 0);
    }
}

// ===========================================================================
// Stage 5b: block-bilinear classifier — R16: i-SPLIT for occupancy.
// R14/R15 post-mortem: VGPR_Count=80 proves the compiler re-serialized the
// written 2-deep pipeline (needs >=128 live VGPRs) -> every i pays a naked
// L2 round trip, and 768 blocks grid-caps occupancy at 12 waves/CU (25%),
// so TLP can't hide it either (dur 88us vs ~18us issue-count model; all
// pipes <35% busy = latency-bound).
// Fix: split the i-range across blockIdx.z in {0,1}: 1536 blocks -> 6
// blocks/CU = 24 waves/CU (VGPR 80 fits the 24-wave budget of ~85; LDS
// 6x18.4KB=110KB <=160). Partial sums merge through the ALREADY-atomic
// output (adds 1.2M extra atomics into 1.6MB — negligible). Everything
// else byte-identical to the R14-verified kernel.
// ===========================================================================
__global__ __launch_bounds__(256) void final_mfma(
    const float* __restrict__ hv,             // [4096][768] f32
    const float* __restrict__ tv,
    const unsigned short* __restrict__ WbT,   // [12][64][2][4][2][4][16][8] bf16
    float* __restrict__ out)                  // [4096][97] f32
{
    int kb   = blockIdx.x;
    int row0 = blockIdx.y * 64;
    int ib   = blockIdx.z * 32;               // i-range [ib, ib+32)
    __shared__ __attribute__((aligned(16))) unsigned short hS[64][72];
    __shared__ __attribute__((aligned(16))) unsigned short tS[64][72];

    int tid = threadIdx.x;
    // stage hv/tv kb-slices (64 rows x 64), f32 -> bf16 on the fly
    for (int e = tid; e < 1024; e += 256) {
        int r = e >> 4, part = e & 15;
        float4 xh = *(const float4*)(hv + (size_t)(row0 + r)*D_ + kb*BLK_ + part*4);
        float4 xt = *(const float4*)(tv + (size_t)(row0 + r)*D_ + kb*BLK_ + part*4);
        ushort4v ph = { f2bf(xh.x), f2bf(xh.y), f2bf(xh.z), f2bf(xh.w) };
        ushort4v pt = { f2bf(xt.x), f2bf(xt.y), f2bf(xt.z), f2bf(xt.w) };
        *(ushort4v*)&hS[r][part*4] = ph;
        *(ushort4v*)&tS[r][part*4] = pt;
    }
    int wave = tid >> 6, lane = tid & 63;
    int wr = wave & 1, wc = wave >> 1;
    int lm = lane & 15, quad = lane >> 4;
    __syncthreads();

    // preload tv fragments as scalar f32 (i-invariant within this kb)
    float tvv[2][2][8];   // [rowtile][jhalf][t]
    #pragma unroll
    for (int rt = 0; rt < 2; ++rt)
        #pragma unroll
        for (int j2 = 0; j2 < 2; ++j2) {
            int r = wr*32 + rt*16 + lm;
            ushort8 w = *(const ushort8*)&tS[r][j2*32 + quad*8];
            #pragma unroll
            for (int t = 0; t < 8; ++t) tvv[rt][j2][t] = bf2f(w[t]);
        }

    f4 acc[2][4] = {};
    // per-lane base into dense frag-packed WbT:
    // frag(i, ct, j2) at bbase + i*8192 + ct*1024 + j2*512  (bf16 units)
    const unsigned short* bbase = WbT + (size_t)kb*(64*128*64)
                                + (size_t)wc*4096 + ((size_t)quad*16 + lm)*8;

    // 2-deep register pipeline over this block's 32 i's, no barriers
    s8 bufA[4][2], bufB[4][2];
    loadB_frag(bbase, ib, bufA);
    for (int ii = 0; ii < 32; ii += 2) {
        int i0 = ib + ii;
        loadB_frag(bbase, i0 + 1, bufB);
        {
            float sh0 = bf2f(hS[wr*32 + lm][i0]);
            float sh1 = bf2f(hS[wr*32 + 16 + lm][i0]);
            compute_i(bufA, sh0, sh1, tvv, acc);
        }
        if (ii < 30) loadB_frag(bbase, i0 + 2, bufA);
        {
            float sh0 = bf2f(hS[wr*32 + lm][i0 + 1]);
            float sh1 = bf2f(hS[wr*32 + 16 + lm][i0 + 1]);
            compute_i(bufB, sh0, sh1, tvv, acc);
        }
    }

    #pragma unroll
    for (int rt = 0; rt < 2; ++rt)
        #pragma unroll
        for (int ct = 0; ct < 4; ++ct)
            #pragma unroll
            for (int r = 0; r < 4; ++r) {
                int row = row0 + wr*32 + rt*16 + quad*4 + r;
                int col = wc*64 + ct*16 + lm;
                if (col < C_) atomicAdd(out + (size_t)row*C_ + col, acc[rt][ct][r]);
            }
}

// ===========================================================================
extern "C" void kernel_launch(void* const* d_in, const int* in_sizes, int n_in,
                              void* d_out, int out_size, void* d_ws, size_t ws_size,
                              hipStream_t stream)
{
    const float* seq_lhs = (const float*)d_in[0];
    const float* ent_lhs = (const float*)d_in[1];
    const float* attn    = (const float*)d_in[2];
    const int*   labels  = (const int*)d_in[3];
    const int*   hts     = (const int*)d_in[4];
    const float* Wh      = (const float*)d_in[5];
    const float* bh      = (const float*)d_in[6];
    const float* Wt      = (const float*)d_in[7];
    const float* bt      = (const float*)d_in[8];
    const float* Wb      = (const float*)d_in[9];
    const float* bb      = (const float*)d_in[10];
    float* out = (float*)d_out;

    float* wsf      = (float*)d_ws;
    float* hv       = wsf;                       // 3145728 f32
    float* tv       = hv + 3145728;              // 3145728 f32
    unsigned short* ent_embB  = (unsigned short*)(tv + 3145728); // 262144
    unsigned short* ent_attnB = ent_embB  + 262144;   // 2097152
    unsigned short* htA       = ent_attnB + 2097152;  // 2097152
    unsigned short* seqT      = htA       + 2097152;  // 2097152
    unsigned short* WhT       = seqT      + 2097152;  // 1572864
    unsigned short* WtT       = WhT       + 1572864;  // 1572864
    unsigned short* Ah        = WtT       + 1572864;  // 8388608 ([4096][2048])
    unsigned short* At        = Ah        + 8388608;  // 8388608
    unsigned short* WbT       = At        + 8388608;  // 6291456
    // total ~90.4 MB

    // weight preps (independent of activations)
    transpose_cvt_W<<<dim3(24, 64, 2), 256, 0, stream>>>(Wh, Wt, WhT, WtT);
    prep_WbT<<<KB_*64, 256, 0, stream>>>(Wb, WbT);
    transpose_cvt_seq<<<dim3(32, 16, B_), 256, 0, stream>>>(seq_lhs, seqT);

    pool_lse<<<B_*E_, 256, 0, stream>>>(ent_lhs, labels, ent_embB);
    pool_attn<<<dim3(E_, B_*NH_), 256, 0, stream>>>(attn, labels, ent_attnB);
    pair_attn_kernel<<<B_*R_, 256, 0, stream>>>(ent_attnB, hts, htA);
    gemm_rel_mfma<<<dim3(8, 8, B_), 256, 0, stream>>>(htA, seqT, Ah, At);
    prep_gather<<<NROW, 256, 0, stream>>>(ent_embB, hts, Ah, At);
    gemm_ext_mfma<<<dim3(6, 32, 2), 256, 0, stream>>>(Ah, At, WhT, WtT, bh, bt, hv, tv);
    out_init<<<(NROW*C_ + 255)/256, 256, 0, stream>>>(bb, out);
    final_mfma<<<dim3(KB_, NROW/64, 2), 256, 0, stream>>>(hv, tv, WbT, out);
}

// Round 9
// 307.113 us; speedup vs baseline: 1.0224x; 1.0224x over previous
//
#include <hip/hip_runtime.h>
#include <hip/hip_bf16.h>
#include <math.h>

// Problem constants
#define B_  4
#define L_  512
#define H_  1024
#define M_  128
#define E_  64
#define NH_ 16
#define R_  1024
#define D_  768
#define BLK_ 64
#define C_  97
#define NROW (B_*R_)          // 4096
#define KB_  (D_/BLK_)        // 12

typedef __attribute__((ext_vector_type(8))) unsigned short ushort8;
typedef __attribute__((ext_vector_type(4))) unsigned short ushort4v;
typedef __attribute__((ext_vector_type(8))) short s8;       // 8 bf16 MFMA operand
typedef __attribute__((ext_vector_type(4))) float f4;       // MFMA C/D

__device__ __forceinline__ unsigned short f2bf(float x) {   // RNE f32->bf16
    unsigned u = __builtin_bit_cast(unsigned, x);
    unsigned r = (u + 0x7fffu + ((u >> 16) & 1u)) >> 16;
    return (unsigned short)r;
}
__device__ __forceinline__ float bf2f(unsigned short h) {
    unsigned u = ((unsigned)h) << 16;
    return __builtin_bit_cast(float, u);
}
__device__ __forceinline__ float lo16f(unsigned u) { return __builtin_bit_cast(float, u << 16); }
__device__ __forceinline__ float hi16f(unsigned u) { return __builtin_bit_cast(float, u & 0xffff0000u); }

// async global->LDS 16B (compiler never auto-emits; m97 lever). LDS dest
// semantics: wave-uniform base + lane*16 — callers must pass lane-linear lds.
__device__ __forceinline__ void gload_lds16(const unsigned short* g, unsigned short* l)
{
    __builtin_amdgcn_global_load_lds(
        (const __attribute__((address_space(1))) unsigned int*)g,
        (__attribute__((address_space(3))) unsigned int*)l, 16, 0, 0);
}

// ===========================================================================
// Stage 1a: entity logsumexp pooling -> bf16 (R9-verified)
// ===========================================================================
__global__ __launch_bounds__(256) void pool_lse(
    const float* __restrict__ ent_lhs, const int* __restrict__ labels,
    unsigned short* __restrict__ ent_embB)
{
    int be = blockIdx.x, b = be >> 6, e = be & 63;
    __shared__ int midx[M_];
    __shared__ int scnt;
    if (threadIdx.x == 0) scnt = 0;
    __syncthreads();
    if (threadIdx.x < M_) {
        if (labels[b*M_ + threadIdx.x] == e) {
            int p = atomicAdd(&scnt, 1);
            midx[p] = threadIdx.x;
        }
    }
    __syncthreads();
    int cnt = scnt;
    for (int h = threadIdx.x; h < H_; h += blockDim.x) {
        float r = 0.f;
        if (cnt > 0) {
            const float* base = ent_lhs + (size_t)b*M_*H_ + h;
            float mx = -INFINITY;
            for (int k = 0; k < cnt; ++k) mx = fmaxf(mx, base[(size_t)midx[k]*H_]);
            float s = 0.f;
            for (int k = 0; k < cnt; ++k) s += expf(base[(size_t)midx[k]*H_] - mx);
            r = mx + logf(s);
        }
        ent_embB[(size_t)be*H_ + h] = f2bf(r);
    }
}

// ===========================================================================
// Stage 1b: entity attention mean -> bf16. grid (E, B*NH)  (R9-verified)
// ===========================================================================
__global__ __launch_bounds__(256) void pool_attn(
    const float* __restrict__ attn, const int* __restrict__ labels,
    unsigned short* __restrict__ ent_attnB)
{
    int e  = blockIdx.x;
    int y  = blockIdx.y;          // b*NH + nh
    int b  = y >> 4, nh = y & 15;
    __shared__ int midx[M_];
    __shared__ int scnt;
    if (threadIdx.x == 0) scnt = 0;
    __syncthreads();
    if (threadIdx.x < M_) {
        if (labels[b*M_ + threadIdx.x] == e) {
            int p = atomicAdd(&scnt, 1);
            midx[p] = threadIdx.x;
        }
    }
    __syncthreads();
    int cnt = scnt;
    float inv = (cnt > 0) ? 1.f/(float)cnt : 0.f;
    const float* base = attn + ((size_t)(b*NH_ + nh)*M_)*L_;
    #pragma unroll
    for (int q = 0; q < 2; ++q) {
        int l = threadIdx.x + q*256;
        float s = 0.f;
        for (int k = 0; k < cnt; ++k) s += base[(size_t)midx[k]*L_ + l];
        ent_attnB[((size_t)(b*E_ + e)*NH_ + nh)*L_ + l] = f2bf(s * inv);
    }
}

// ===========================================================================
// Stage 2: pair attention — R18: WAVE-PER-PAIR. Old form: 4096 tiny blocks
// (one pair each, LDS+barrier cross-wave reduce) — launch/latency-bound.
// New: 1024 blocks x 4 waves, each wave owns one pair; lane covers 4 chunks
// of the 256 u32 columns; 8 independent coalesced loads per nh iter; wave-
// only __shfl_xor reduction (no LDS, no barrier). Same math/output layout.
// ===========================================================================
__global__ __launch_bounds__(256) void pair_attn_kernel(
    const unsigned short* __restrict__ entA, const int* __restrict__ hts,
    unsigned short* __restrict__ htA)
{
    int w  = threadIdx.x >> 6, ln = threadIdx.x & 63;
    int br = blockIdx.x*4 + w, b = br >> 10;
    int hi = hts[br*2 + 0], ti = hts[br*2 + 1];
    const unsigned* ph = (const unsigned*)(entA + ((size_t)(b*E_ + hi)*NH_)*L_);
    const unsigned* pt = (const unsigned*)(entA + ((size_t)(b*E_ + ti)*NH_)*L_);
    float v0[4] = {0.f, 0.f, 0.f, 0.f};
    float v1[4] = {0.f, 0.f, 0.f, 0.f};
    #pragma unroll
    for (int nh = 0; nh < NH_; ++nh) {
        #pragma unroll
        for (int c = 0; c < 4; ++c) {
            int l2 = ln + c*64;
            unsigned a = ph[nh*(L_/2) + l2], d = pt[nh*(L_/2) + l2];
            v0[c] += lo16f(a)*lo16f(d);
            v1[c] += hi16f(a)*hi16f(d);
        }
    }
    float part = 0.f;
    #pragma unroll
    for (int c = 0; c < 4; ++c) part += v0[c] + v1[c];
    #pragma unroll
    for (int off = 32; off > 0; off >>= 1) part += __shfl_xor(part, off, 64);
    float norm = 1.f / (part*(1.f/16.f) + 1e-5f);   // denom on sum of nh-means
    #pragma unroll
    for (int c = 0; c < 4; ++c) {
        unsigned short o0 = f2bf(v0[c]*(1.f/16.f)*norm);
        unsigned short o1 = f2bf(v1[c]*(1.f/16.f)*norm);
        *(unsigned*)(htA + (size_t)br*L_ + (size_t)(ln + c*64)*2) = ((unsigned)o1 << 16) | o0;
    }
}

// ===========================================================================
// Preps (R8-verified)
// ===========================================================================
__global__ __launch_bounds__(256) void transpose_cvt_seq(const float* __restrict__ in,
                                                         unsigned short* __restrict__ outp)
{
    int b = blockIdx.z;
    int h0 = blockIdx.x*32, l0 = blockIdx.y*32;
    __shared__ float tile[32][33];
    int tx = threadIdx.x & 31, ty = threadIdx.x >> 5;
    #pragma unroll
    for (int p = 0; p < 4; ++p)
        tile[ty + p*8][tx] = in[((size_t)b*L_ + l0 + ty + p*8)*H_ + h0 + tx];
    __syncthreads();
    #pragma unroll
    for (int p = 0; p < 4; ++p)
        outp[((size_t)b*H_ + h0 + ty + p*8)*L_ + l0 + tx] = f2bf(tile[tx][ty + p*8]);
}

__global__ __launch_bounds__(256) void transpose_cvt_W(const float* __restrict__ Wh,
                                                       const float* __restrict__ Wt,
                                                       unsigned short* __restrict__ WhT,
                                                       unsigned short* __restrict__ WtT)
{
    const float* in = blockIdx.z ? Wt : Wh;
    unsigned short* outp = blockIdx.z ? WtT : WhT;
    int n0 = blockIdx.x*32, k0 = blockIdx.y*32;
    __shared__ float tile[32][33];
    int tx = threadIdx.x & 31, ty = threadIdx.x >> 5;
    #pragma unroll
    for (int p = 0; p < 4; ++p)
        tile[ty + p*8][tx] = in[((size_t)(k0 + ty + p*8))*D_ + n0 + tx];
    __syncthreads();
    #pragma unroll
    for (int p = 0; p < 4; ++p) {
        int n = n0 + ty + p*8;
        outp[(size_t)n*2048 + k0 + tx] = f2bf(tile[tx][ty + p*8]);
    }
}

// gather ent rows (bf16 copy) into Ah/At cols [0,1024)  (R8-verified)
__global__ __launch_bounds__(256) void prep_gather(const unsigned short* __restrict__ entE,
                                                   const int* __restrict__ hts,
                                                   unsigned short* __restrict__ Ah,
                                                   unsigned short* __restrict__ At)
{
    int n = blockIdx.x, b = n >> 10;
    int m = threadIdx.x >> 7, off = (threadIdx.x & 127)*8;
    int idx = hts[n*2 + m];
    const unsigned short* src = entE + (size_t)(b*E_ + idx)*H_ + off;
    unsigned short* dst = (m ? At : Ah) + (size_t)n*2048 + off;
    *(ushort8*)dst = *(const ushort8*)src;
}

// WbT layout (R14): fragment-packed DENSE per wave-instruction.
// Element (i, c=wc*64+ct*16+lm, j=j2*32+quad*8+t) stored at
//   [kb][i][wc][ct][j2][quad][lm][t]
__global__ __launch_bounds__(256) void prep_WbT(const float* __restrict__ Wb,
                                                unsigned short* __restrict__ outp)
{
    int blk = blockIdx.x;                 // kb*64 + i
    __shared__ float sW[64*97];
    const float* src = Wb + (size_t)blk*64*97;
    for (int e = threadIdx.x; e < 64*97; e += 256) sW[e] = src[e];
    __syncthreads();
    unsigned short* dst = outp + (size_t)blk*128*64;
    for (int e = threadIdx.x; e < 128*64; e += 256) {
        int wcq = e >> 12;            // wc
        int ct  = (e >> 10) & 3;
        int j2  = (e >> 9) & 1;
        int qd  = (e >> 7) & 3;
        int lm  = (e >> 3) & 15;
        int t   = e & 7;
        int c   = wcq*64 + ct*16 + lm;
        int j   = j2*32 + qd*8 + t;   // k-index pairing preserved (R8 algebra)
        dst[e] = (c < C_) ? f2bf(sW[j*97 + c]) : (unsigned short)0;
    }
}

// ===========================================================================
// bf16 MFMA GEMM core — R15-verified: async global_load_lds staging.
// As/Bs UNPADDED [128][32] so lds_byte = ch*16 is lane-linear (m173).
// ===========================================================================
__device__ __forceinline__ void gemm128_core(const unsigned short* __restrict__ A,
                                             const unsigned short* __restrict__ Bt,
                                             int K, int row0, int col0,
                                             f4 (&acc)[4][4])
{
    __shared__ __attribute__((aligned(16))) unsigned short As[128][32];
    __shared__ __attribute__((aligned(16))) unsigned short Bs[128][32];
    int tid = threadIdx.x;
    int wave = tid >> 6, lane = tid & 63;
    int wr = wave & 1, wc = wave >> 1;
    int lm = lane & 15, quad = lane >> 4;

    for (int k0 = 0; k0 < K; k0 += 32) {
        #pragma unroll
        for (int s = 0; s < 2; ++s) {
            int ch = tid + s*256;
            int row = ch >> 2, part = ch & 3;     // lds_byte = ch*16 (lane-linear)
            gload_lds16(A  + (size_t)(row0 + row)*K + k0 + part*8, &As[0][0] + ch*8);
            gload_lds16(Bt + (size_t)(col0 + row)*K + k0 + part*8, &Bs[0][0] + ch*8);
        }
        __syncthreads();   // compiler drains vmcnt(0) before s_barrier
        s8 a[4], b[4];
        #pragma unroll
        for (int ti = 0; ti < 4; ++ti) a[ti] = *(const s8*)&As[wr*64 + ti*16 + lm][quad*8];
        #pragma unroll
        for (int tj = 0; tj < 4; ++tj) b[tj] = *(const s8*)&Bs[wc*64 + tj*16 + lm][quad*8];
        #pragma unroll
        for (int ti = 0; ti < 4; ++ti)
            #pragma unroll
            for (int tj = 0; tj < 4; ++tj)
                acc[ti][tj] = __builtin_amdgcn_mfma_f32_16x16x32_bf16(a[ti], b[tj], acc[ti][tj], 0, 0, 0);
        __syncthreads();
    }
}

// ===========================================================================
// Stage 3: rel GEMM -> bf16 into Ah/At cols [1024,2048)  (R8-verified)
// ===========================================================================
__global__ __launch_bounds__(256) void gemm_rel_mfma(const unsigned short* __restrict__ htA,
                                                     const unsigned short* __restrict__ seqT,
                                                     unsigned short* __restrict__ Ah,
                                                     unsigned short* __restrict__ At)
{
    int z = blockIdx.z;
    const unsigned short* A  = htA  + (size_t)z*R_*L_;
    const unsigned short* Bt = seqT + (size_t)z*H_*L_;
    int row0 = blockIdx.y*128, col0 = blockIdx.x*128;
    f4 acc[4][4] = {};
    gemm128_core(A, Bt, L_, row0, col0, acc);
    int lane = threadIdx.x & 63, wave = threadIdx.x >> 6;
    int wr = wave & 1, wc = wave >> 1, lm = lane & 15, quad = lane >> 4;
    #pragma unroll
    for (int ti = 0; ti < 4; ++ti)
        #pragma unroll
        for (int tj = 0; tj < 4; ++tj)
            #pragma unroll
            for (int r = 0; r < 4; ++r) {
                int n   = z*R_ + row0 + wr*64 + ti*16 + quad*4 + r;
                int col = col0 + wc*64 + tj*16 + lm;
                unsigned short v = f2bf(acc[ti][tj][r]);
                Ah[(size_t)n*2048 + 1024 + col] = v;
                At[(size_t)n*2048 + 1024 + col] = v;
            }
}

// ===========================================================================
// Stage 4: extractor GEMM (K=2048) + bias + tanh -> f32 hv/tv
// ===========================================================================
__global__ __launch_bounds__(256) void gemm_ext_mfma(
    const unsigned short* __restrict__ Ah, const unsigned short* __restrict__ At,
    const unsigned short* __restrict__ WhT, const unsigned short* __restrict__ WtT,
    const float* __restrict__ bh, const float* __restrict__ bt,
    float* __restrict__ hv, float* __restrict__ tv)
{
    int z = blockIdx.z;
    const unsigned short* A  = z ? At  : Ah;
    const unsigned short* Bt = z ? WtT : WhT;
    const float* bias = z ? bt : bh;
    float* C = z ? tv : hv;
    int row0 = blockIdx.y*128, col0 = blockIdx.x*128;
    f4 acc[4][4] = {};
    gemm128_core(A, Bt, 2048, row0, col0, acc);
    int lane = threadIdx.x & 63, wave = threadIdx.x >> 6;
    int wr = wave & 1, wc = wave >> 1, lm = lane & 15, quad = lane >> 4;
    #pragma unroll
    for (int ti = 0; ti < 4; ++ti)
        #pragma unroll
        for (int tj = 0; tj < 4; ++tj)
            #pragma unroll
            for (int r = 0; r < 4; ++r) {
                int row = row0 + wr*64 + ti*16 + quad*4 + r;
                int col = col0 + wc*64 + tj*16 + lm;
                float x = acc[ti][tj][r] + bias[col];
                float e = __expf(2.f*x);
                C[(size_t)row*D_ + col] = 1.f - 2.f/(e + 1.f);   // tanh
            }
}

// ===========================================================================
// Stage 5a: init output with bias
// ===========================================================================
__global__ void out_init(const float* __restrict__ bb, float* __restrict__ out)
{
    int i = blockIdx.x*256 + threadIdx.x;
    if (i < NROW*C_) out[i] = bb[i % C_];
}

// ===========================================================================
// Stage 5b helpers (R14-verified): direct-L2 B-frag load + one-i compute.
// ===========================================================================
__device__ __forceinline__ void loadB_frag(const unsigned short* __restrict__ bbase,
                                           int i, s8 (&dst)[4][2])
{
    #pragma unroll
    for (int ct = 0; ct < 4; ++ct) {
        dst[ct][0] = *(const s8*)(bbase + (size_t)i*8192 + ct*1024);
        dst[ct][1] = *(const s8*)(bbase + (size_t)i*8192 + ct*1024 + 512);
    }
}

__device__ __forceinline__ void compute_i(const s8 (&bfr)[4][2],
                                          float sh0, float sh1,
                                          const float (&tvv)[2][2][8],
                                          f4 (&acc)[2][4])
{
    // A-frags: bf16-truncate(hv_i * tv) packed via v_perm (R9-verified path)
    s8 afr0[2], afr1[2];
    #pragma unroll
    for (int j2 = 0; j2 < 2; ++j2) {
        union { unsigned u[4]; s8 v; } c0, c1;
        #pragma unroll
        for (int t2 = 0; t2 < 4; ++t2) {
            float pe0 = sh0 * tvv[0][j2][t2*2];
            float po0 = sh0 * tvv[0][j2][t2*2 + 1];
            float pe1 = sh1 * tvv[1][j2][t2*2];
            float po1 = sh1 * tvv[1][j2][t2*2 + 1];
            c0.u[t2] = __builtin_amdgcn_perm(__builtin_bit_cast(unsigned, po0),
                                             __builtin_bit_cast(unsigned, pe0),
                                             0x07060302u);
            c1.u[t2] = __builtin_amdgcn_perm(__builtin_bit_cast(unsigned, po1),
                                             __builtin_bit_cast(unsigned, pe1),
                                             0x07060302u);
        }
        afr0[j2] = c0.v; afr1[j2] = c1.v;
    }
    #pragma unroll
    for (int ct = 0; ct < 4; ++ct) {
        acc[0][ct] = __builtin_amdgcn_mfma_f32_16x16x32_bf16(afr0[0], bfr[ct][0], acc[0][ct], 0, 0, 0);
        acc[0][ct] = __builtin_amdgcn_mfma_f32_16x16x32_bf16(afr0[1], bfr[ct][1], acc[0][ct], 0, 0, 0);
        acc[1][ct] = __builtin_amdgcn_mfma_f32_16x16x32_bf16(afr1[0], bfr[ct][0], acc[1][ct], 0, 0, 0);
        acc[1][ct] = __builtin_amdgcn_mfma_f32_16x16x32_bf16(afr1[1], bfr[ct][1], acc[1][ct], 0, 0, 0);
    }
}

// ===========================================================================
// Stage 5b: block-bilinear classifier — R18 (= R17 retry; R8 bench was an
// infra container failure, no verdict): sched_barrier(0)-pinned 2-deep
// register pipeline over the direct-L2 dense frag-packed WbT.
// Theory: R14-R16 compiled to VGPR~80-84 — compiler sinks prefetch loads to
// right-before-use, re-serializing load->vmcnt->compute each i (latency-
// bound at ~2 resident blocks/CU; R16 proved occupancy can't be raised).
// sched_barrier(0) after each prefetch forbids the sink: i+1's 8 loads
// issue BEFORE i's ~260cy compute. Success marker: VGPR_Count ~116-128.
// ===========================================================================
__global__ __launch_bounds__(256) void final_mfma(
    const float* __restrict__ hv,             // [4096][768] f32
    const float* __restrict__ tv,
    const unsigned short* __restrict__ WbT,   // [12][64][2][4][2][4][16][8] bf16
    float* __restrict__ out)                  // [4096][97] f32
{
    int kb   = blockIdx.x;
    int row0 = blockIdx.y * 64;
    __shared__ __attribute__((aligned(16))) unsigned short hS[64][72];
    __shared__ __attribute__((aligned(16))) unsigned short tS[64][72];

    int tid = threadIdx.x;
    // stage hv/tv kb-slices (64 rows x 64), f32 -> bf16 on the fly
    for (int e = tid; e < 1024; e += 256) {
        int r = e >> 4, part = e & 15;
        float4 xh = *(const float4*)(hv + (size_t)(row0 + r)*D_ + kb*BLK_ + part*4);
        float4 xt = *(const float4*)(tv + (size_t)(row0 + r)*D_ + kb*BLK_ + part*4);
        ushort4v ph = { f2bf(xh.x), f2bf(xh.y), f2bf(xh.z), f2bf(xh.w) };
        ushort4v pt = { f2bf(xt.x), f2bf(xt.y), f2bf(xt.z), f2bf(xt.w) };
        *(ushort4v*)&hS[r][part*4] = ph;
        *(ushort4v*)&tS[r][part*4] = pt;
    }
    int wave = tid >> 6, lane = tid & 63;
    int wr = wave & 1, wc = wave >> 1;
    int lm = lane & 15, quad = lane >> 4;
    __syncthreads();

    // preload tv fragments as scalar f32 (i-invariant within this kb)
    float tvv[2][2][8];   // [rowtile][jhalf][t]
    #pragma unroll
    for (int rt = 0; rt < 2; ++rt)
        #pragma unroll
        for (int j2 = 0; j2 < 2; ++j2) {
            int r = wr*32 + rt*16 + lm;
            ushort8 w = *(const ushort8*)&tS[r][j2*32 + quad*8];
            #pragma unroll
            for (int t = 0; t < 8; ++t) tvv[rt][j2][t] = bf2f(w[t]);
        }

    f4 acc[2][4] = {};
    // per-lane base into dense frag-packed WbT:
    // frag(i, ct, j2) at bbase + i*8192 + ct*1024 + j2*512  (bf16 units)
    const unsigned short* bbase = WbT + (size_t)kb*(64*128*64)
                                + (size_t)wc*4096 + ((size_t)quad*16 + lm)*8;

    // 2-deep register pipeline over i; sched_barrier(0) pins prefetch issue
    s8 bufA[4][2], bufB[4][2];
    loadB_frag(bbase, 0, bufA);
    for (int i0 = 0; i0 < 64; i0 += 2) {
        loadB_frag(bbase, i0 + 1, bufB);
        __builtin_amdgcn_sched_barrier(0);    // bufB loads issued BEFORE bufA compute
        {
            float sh0 = bf2f(hS[wr*32 + lm][i0]);
            float sh1 = bf2f(hS[wr*32 + 16 + lm][i0]);
            compute_i(bufA, sh0, sh1, tvv, acc);
        }
        if (i0 < 62) loadB_frag(bbase, i0 + 2, bufA);
        __builtin_amdgcn_sched_barrier(0);    // bufA loads issued BEFORE bufB compute
        {
            float sh0 = bf2f(hS[wr*32 + lm][i0 + 1]);
            float sh1 = bf2f(hS[wr*32 + 16 + lm][i0 + 1]);
            compute_i(bufB, sh0, sh1, tvv, acc);
        }
    }

    #pragma unroll
    for (int rt = 0; rt < 2; ++rt)
        #pragma unroll
        for (int ct = 0; ct < 4; ++ct)
            #pragma unroll
            for (int r = 0; r < 4; ++r) {
                int row = row0 + wr*32 + rt*16 + quad*4 + r;
                int col = wc*64 + ct*16 + lm;
                if (col < C_) atomicAdd(out + (size_t)row*C_ + col, acc[rt][ct][r]);
            }
}

// ===========================================================================
extern "C" void kernel_launch(void* const* d_in, const int* in_sizes, int n_in,
                              void* d_out, int out_size, void* d_ws, size_t ws_size,
                              hipStream_t stream)
{
    const float* seq_lhs = (const float*)d_in[0];
    const float* ent_lhs = (const float*)d_in[1];
    const float* attn    = (const float*)d_in[2];
    const int*   labels  = (const int*)d_in[3];
    const int*   hts     = (const int*)d_in[4];
    const float* Wh      = (const float*)d_in[5];
    const float* bh      = (const float*)d_in[6];
    const float* Wt      = (const float*)d_in[7];
    const float* bt      = (const float*)d_in[8];
    const float* Wb      = (const float*)d_in[9];
    const float* bb      = (const float*)d_in[10];
    float* out = (float*)d_out;

    float* wsf      = (float*)d_ws;
    float* hv       = wsf;                       // 3145728 f32
    float* tv       = hv + 3145728;              // 3145728 f32
    unsigned short* ent_embB  = (unsigned short*)(tv + 3145728); // 262144
    unsigned short* ent_attnB = ent_embB  + 262144;   // 2097152
    unsigned short* htA       = ent_attnB + 2097152;  // 2097152
    unsigned short* seqT      = htA       + 2097152;  // 2097152
    unsigned short* WhT       = seqT      + 2097152;  // 1572864
    unsigned short* WtT       = WhT       + 1572864;  // 1572864
    unsigned short* Ah        = WtT       + 1572864;  // 8388608 ([4096][2048])
    unsigned short* At        = Ah        + 8388608;  // 8388608
    unsigned short* WbT       = At        + 8388608;  // 6291456
    // total ~90.4 MB

    // weight preps (independent of activations)
    transpose_cvt_W<<<dim3(24, 64, 2), 256, 0, stream>>>(Wh, Wt, WhT, WtT);
    prep_WbT<<<KB_*64, 256, 0, stream>>>(Wb, WbT);
    transpose_cvt_seq<<<dim3(32, 16, B_), 256, 0, stream>>>(seq_lhs, seqT);

    pool_lse<<<B_*E_, 256, 0, stream>>>(ent_lhs, labels, ent_embB);
    pool_attn<<<dim3(E_, B_*NH_), 256, 0, stream>>>(attn, labels, ent_attnB);
    pair_attn_kernel<<<B_*R_/4, 256, 0, stream>>>(ent_attnB, hts, htA);
    gemm_rel_mfma<<<dim3(8, 8, B_), 256, 0, stream>>>(htA, seqT, Ah, At);
    prep_gather<<<NROW, 256, 0, stream>>>(ent_embB, hts, Ah, At);
    gemm_ext_mfma<<<dim3(6, 32, 2), 256, 0, stream>>>(Ah, At, WhT, WtT, bh, bt, hv, tv);
    out_init<<<(NROW*C_ + 255)/256, 256, 0, stream>>>(bb, out);
    final_mfma<<<dim3(KB_, NROW/64), 256, 0, stream>>>(hv, tv, WbT, out);
}

// Round 10
// 300.447 us; speedup vs baseline: 1.0450x; 1.0222x over previous
//
#include <hip/hip_runtime.h>
#include <hip/hip_bf16.h>
#include <math.h>

// Problem constants
#define B_  4
#define L_  512
#define H_  1024
#define M_  128
#define E_  64
#define NH_ 16
#define R_  1024
#define D_  768
#define BLK_ 64
#define C_  97
#define NROW (B_*R_)          // 4096
#define KB_  (D_/BLK_)        // 12

typedef __attribute__((ext_vector_type(8))) unsigned short ushort8;
typedef __attribute__((ext_vector_type(4))) unsigned short ushort4v;
typedef __attribute__((ext_vector_type(8))) short s8;       // 8 bf16 MFMA operand
typedef __attribute__((ext_vector_type(4))) float f4;       // MFMA C/D

__device__ __forceinline__ unsigned short f2bf(float x) {   // RNE f32->bf16
    unsigned u = __builtin_bit_cast(unsigned, x);
    unsigned r = (u + 0x7fffu + ((u >> 16) & 1u)) >> 16;
    return (unsigned short)r;
}
__device__ __forceinline__ float bf2f(unsigned short h) {
    unsigned u = ((unsigned)h) << 16;
    return __builtin_bit_cast(float, u);
}
__device__ __forceinline__ float lo16f(unsigned u) { return __builtin_bit_cast(float, u << 16); }
__device__ __forceinline__ float hi16f(unsigned u) { return __builtin_bit_cast(float, u & 0xffff0000u); }

// async global->LDS 16B (compiler never auto-emits; m97 lever). LDS dest
// semantics: wave-uniform base + lane*16 — callers must pass lane-linear lds.
__device__ __forceinline__ void gload_lds16(const unsigned short* g, unsigned short* l)
{
    __builtin_amdgcn_global_load_lds(
        (const __attribute__((address_space(1))) unsigned int*)g,
        (__attribute__((address_space(3))) unsigned int*)l, 16, 0, 0);
}

// ===========================================================================
// Stage 1a: entity logsumexp pooling -> bf16 (R9-verified)
// ===========================================================================
__global__ __launch_bounds__(256) void pool_lse(
    const float* __restrict__ ent_lhs, const int* __restrict__ labels,
    unsigned short* __restrict__ ent_embB)
{
    int be = blockIdx.x, b = be >> 6, e = be & 63;
    __shared__ int midx[M_];
    __shared__ int scnt;
    if (threadIdx.x == 0) scnt = 0;
    __syncthreads();
    if (threadIdx.x < M_) {
        if (labels[b*M_ + threadIdx.x] == e) {
            int p = atomicAdd(&scnt, 1);
            midx[p] = threadIdx.x;
        }
    }
    __syncthreads();
    int cnt = scnt;
    for (int h = threadIdx.x; h < H_; h += blockDim.x) {
        float r = 0.f;
        if (cnt > 0) {
            const float* base = ent_lhs + (size_t)b*M_*H_ + h;
            float mx = -INFINITY;
            for (int k = 0; k < cnt; ++k) mx = fmaxf(mx, base[(size_t)midx[k]*H_]);
            float s = 0.f;
            for (int k = 0; k < cnt; ++k) s += expf(base[(size_t)midx[k]*H_] - mx);
            r = mx + logf(s);
        }
        ent_embB[(size_t)be*H_ + h] = f2bf(r);
    }
}

// ===========================================================================
// Stage 1b: entity attention mean -> bf16. grid (E, B*NH)  (R9-verified)
// ===========================================================================
__global__ __launch_bounds__(256) void pool_attn(
    const float* __restrict__ attn, const int* __restrict__ labels,
    unsigned short* __restrict__ ent_attnB)
{
    int e  = blockIdx.x;
    int y  = blockIdx.y;          // b*NH + nh
    int b  = y >> 4, nh = y & 15;
    __shared__ int midx[M_];
    __shared__ int scnt;
    if (threadIdx.x == 0) scnt = 0;
    __syncthreads();
    if (threadIdx.x < M_) {
        if (labels[b*M_ + threadIdx.x] == e) {
            int p = atomicAdd(&scnt, 1);
            midx[p] = threadIdx.x;
        }
    }
    __syncthreads();
    int cnt = scnt;
    float inv = (cnt > 0) ? 1.f/(float)cnt : 0.f;
    const float* base = attn + ((size_t)(b*NH_ + nh)*M_)*L_;
    #pragma unroll
    for (int q = 0; q < 2; ++q) {
        int l = threadIdx.x + q*256;
        float s = 0.f;
        for (int k = 0; k < cnt; ++k) s += base[(size_t)midx[k]*L_ + l];
        ent_attnB[((size_t)(b*E_ + e)*NH_ + nh)*L_ + l] = f2bf(s * inv);
    }
}

// ===========================================================================
// Stage 2: pair attention — R18-verified WAVE-PER-PAIR (no LDS, no barrier).
// ===========================================================================
__global__ __launch_bounds__(256) void pair_attn_kernel(
    const unsigned short* __restrict__ entA, const int* __restrict__ hts,
    unsigned short* __restrict__ htA)
{
    int w  = threadIdx.x >> 6, ln = threadIdx.x & 63;
    int br = blockIdx.x*4 + w, b = br >> 10;
    int hi = hts[br*2 + 0], ti = hts[br*2 + 1];
    const unsigned* ph = (const unsigned*)(entA + ((size_t)(b*E_ + hi)*NH_)*L_);
    const unsigned* pt = (const unsigned*)(entA + ((size_t)(b*E_ + ti)*NH_)*L_);
    float v0[4] = {0.f, 0.f, 0.f, 0.f};
    float v1[4] = {0.f, 0.f, 0.f, 0.f};
    #pragma unroll
    for (int nh = 0; nh < NH_; ++nh) {
        #pragma unroll
        for (int c = 0; c < 4; ++c) {
            int l2 = ln + c*64;
            unsigned a = ph[nh*(L_/2) + l2], d = pt[nh*(L_/2) + l2];
            v0[c] += lo16f(a)*lo16f(d);
            v1[c] += hi16f(a)*hi16f(d);
        }
    }
    float part = 0.f;
    #pragma unroll
    for (int c = 0; c < 4; ++c) part += v0[c] + v1[c];
    #pragma unroll
    for (int off = 32; off > 0; off >>= 1) part += __shfl_xor(part, off, 64);
    float norm = 1.f / (part*(1.f/16.f) + 1e-5f);   // denom on sum of nh-means
    #pragma unroll
    for (int c = 0; c < 4; ++c) {
        unsigned short o0 = f2bf(v0[c]*(1.f/16.f)*norm);
        unsigned short o1 = f2bf(v1[c]*(1.f/16.f)*norm);
        *(unsigned*)(htA + (size_t)br*L_ + (size_t)(ln + c*64)*2) = ((unsigned)o1 << 16) | o0;
    }
}

// ===========================================================================
// Preps (R8-verified)
// ===========================================================================
__global__ __launch_bounds__(256) void transpose_cvt_seq(const float* __restrict__ in,
                                                         unsigned short* __restrict__ outp)
{
    int b = blockIdx.z;
    int h0 = blockIdx.x*32, l0 = blockIdx.y*32;
    __shared__ float tile[32][33];
    int tx = threadIdx.x & 31, ty = threadIdx.x >> 5;
    #pragma unroll
    for (int p = 0; p < 4; ++p)
        tile[ty + p*8][tx] = in[((size_t)b*L_ + l0 + ty + p*8)*H_ + h0 + tx];
    __syncthreads();
    #pragma unroll
    for (int p = 0; p < 4; ++p)
        outp[((size_t)b*H_ + h0 + ty + p*8)*L_ + l0 + tx] = f2bf(tile[tx][ty + p*8]);
}

__global__ __launch_bounds__(256) void transpose_cvt_W(const float* __restrict__ Wh,
                                                       const float* __restrict__ Wt,
                                                       unsigned short* __restrict__ WhT,
                                                       unsigned short* __restrict__ WtT)
{
    const float* in = blockIdx.z ? Wt : Wh;
    unsigned short* outp = blockIdx.z ? WtT : WhT;
    int n0 = blockIdx.x*32, k0 = blockIdx.y*32;
    __shared__ float tile[32][33];
    int tx = threadIdx.x & 31, ty = threadIdx.x >> 5;
    #pragma unroll
    for (int p = 0; p < 4; ++p)
        tile[ty + p*8][tx] = in[((size_t)(k0 + ty + p*8))*D_ + n0 + tx];
    __syncthreads();
    #pragma unroll
    for (int p = 0; p < 4; ++p) {
        int n = n0 + ty + p*8;
        outp[(size_t)n*2048 + k0 + tx] = f2bf(tile[tx][ty + p*8]);
    }
}

// gather ent rows (bf16 copy) into Ah/At cols [0,1024)  (R8-verified)
__global__ __launch_bounds__(256) void prep_gather(const unsigned short* __restrict__ entE,
                                                   const int* __restrict__ hts,
                                                   unsigned short* __restrict__ Ah,
                                                   unsigned short* __restrict__ At)
{
    int n = blockIdx.x, b = n >> 10;
    int m = threadIdx.x >> 7, off = (threadIdx.x & 127)*8;
    int idx = hts[n*2 + m];
    const unsigned short* src = entE + (size_t)(b*E_ + idx)*H_ + off;
    unsigned short* dst = (m ? At : Ah) + (size_t)n*2048 + off;
    *(ushort8*)dst = *(const ushort8*)src;
}

// WbT layout (R14): fragment-packed DENSE per wave-instruction.
// Element (i, c=wc*64+ct*16+lm, j=j2*32+quad*8+t) stored at
//   [kb][i][wc][ct][j2][quad][lm][t]
__global__ __launch_bounds__(256) void prep_WbT(const float* __restrict__ Wb,
                                                unsigned short* __restrict__ outp)
{
    int blk = blockIdx.x;                 // kb*64 + i
    __shared__ float sW[64*97];
    const float* src = Wb + (size_t)blk*64*97;
    for (int e = threadIdx.x; e < 64*97; e += 256) sW[e] = src[e];
    __syncthreads();
    unsigned short* dst = outp + (size_t)blk*128*64;
    for (int e = threadIdx.x; e < 128*64; e += 256) {
        int wcq = e >> 12;            // wc
        int ct  = (e >> 10) & 3;
        int j2  = (e >> 9) & 1;
        int qd  = (e >> 7) & 3;
        int lm  = (e >> 3) & 15;
        int t   = e & 7;
        int c   = wcq*64 + ct*16 + lm;
        int j   = j2*32 + qd*8 + t;   // k-index pairing preserved (R8 algebra)
        dst[e] = (c < C_) ? f2bf(sW[j*97 + c]) : (unsigned short)0;
    }
}

// ===========================================================================
// bf16 MFMA GEMM core — R15-verified: async global_load_lds staging.
// As/Bs UNPADDED [128][32] so lds_byte = ch*16 is lane-linear (m173).
// ===========================================================================
__device__ __forceinline__ void gemm128_core(const unsigned short* __restrict__ A,
                                             const unsigned short* __restrict__ Bt,
                                             int K, int row0, int col0,
                                             f4 (&acc)[4][4])
{
    __shared__ __attribute__((aligned(16))) unsigned short As[128][32];
    __shared__ __attribute__((aligned(16))) unsigned short Bs[128][32];
    int tid = threadIdx.x;
    int wave = tid >> 6, lane = tid & 63;
    int wr = wave & 1, wc = wave >> 1;
    int lm = lane & 15, quad = lane >> 4;

    for (int k0 = 0; k0 < K; k0 += 32) {
        #pragma unroll
        for (int s = 0; s < 2; ++s) {
            int ch = tid + s*256;
            int row = ch >> 2, part = ch & 3;     // lds_byte = ch*16 (lane-linear)
            gload_lds16(A  + (size_t)(row0 + row)*K + k0 + part*8, &As[0][0] + ch*8);
            gload_lds16(Bt + (size_t)(col0 + row)*K + k0 + part*8, &Bs[0][0] + ch*8);
        }
        __syncthreads();   // compiler drains vmcnt(0) before s_barrier
        s8 a[4], b[4];
        #pragma unroll
        for (int ti = 0; ti < 4; ++ti) a[ti] = *(const s8*)&As[wr*64 + ti*16 + lm][quad*8];
        #pragma unroll
        for (int tj = 0; tj < 4; ++tj) b[tj] = *(const s8*)&Bs[wc*64 + tj*16 + lm][quad*8];
        #pragma unroll
        for (int ti = 0; ti < 4; ++ti)
            #pragma unroll
            for (int tj = 0; tj < 4; ++tj)
                acc[ti][tj] = __builtin_amdgcn_mfma_f32_16x16x32_bf16(a[ti], b[tj], acc[ti][tj], 0, 0, 0);
        __syncthreads();
    }
}

// ===========================================================================
// Stage 3: rel GEMM -> bf16 into Ah/At cols [1024,2048)  (R8-verified)
// ===========================================================================
__global__ __launch_bounds__(256) void gemm_rel_mfma(const unsigned short* __restrict__ htA,
                                                     const unsigned short* __restrict__ seqT,
                                                     unsigned short* __restrict__ Ah,
                                                     unsigned short* __restrict__ At)
{
    int z = blockIdx.z;
    const unsigned short* A  = htA  + (size_t)z*R_*L_;
    const unsigned short* Bt = seqT + (size_t)z*H_*L_;
    int row0 = blockIdx.y*128, col0 = blockIdx.x*128;
    f4 acc[4][4] = {};
    gemm128_core(A, Bt, L_, row0, col0, acc);
    int lane = threadIdx.x & 63, wave = threadIdx.x >> 6;
    int wr = wave & 1, wc = wave >> 1, lm = lane & 15, quad = lane >> 4;
    #pragma unroll
    for (int ti = 0; ti < 4; ++ti)
        #pragma unroll
        for (int tj = 0; tj < 4; ++tj)
            #pragma unroll
            for (int r = 0; r < 4; ++r) {
                int n   = z*R_ + row0 + wr*64 + ti*16 + quad*4 + r;
                int col = col0 + wc*64 + tj*16 + lm;
                unsigned short v = f2bf(acc[ti][tj][r]);
                Ah[(size_t)n*2048 + 1024 + col] = v;
                At[(size_t)n*2048 + 1024 + col] = v;
            }
}

// ===========================================================================
// Stage 4: extractor GEMM (K=2048) + bias + tanh -> f32 hv/tv
// ===========================================================================
__global__ __launch_bounds__(256) void gemm_ext_mfma(
    const unsigned short* __restrict__ Ah, const unsigned short* __restrict__ At,
    const unsigned short* __restrict__ WhT, const unsigned short* __restrict__ WtT,
    const float* __restrict__ bh, const float* __restrict__ bt,
    float* __restrict__ hv, float* __restrict__ tv)
{
    int z = blockIdx.z;
    const unsigned short* A  = z ? At  : Ah;
    const unsigned short* Bt = z ? WtT : WhT;
    const float* bias = z ? bt : bh;
    float* C = z ? tv : hv;
    int row0 = blockIdx.y*128, col0 = blockIdx.x*128;
    f4 acc[4][4] = {};
    gemm128_core(A, Bt, 2048, row0, col0, acc);
    int lane = threadIdx.x & 63, wave = threadIdx.x >> 6;
    int wr = wave & 1, wc = wave >> 1, lm = lane & 15, quad = lane >> 4;
    #pragma unroll
    for (int ti = 0; ti < 4; ++ti)
        #pragma unroll
        for (int tj = 0; tj < 4; ++tj)
            #pragma unroll
            for (int r = 0; r < 4; ++r) {
                int row = row0 + wr*64 + ti*16 + quad*4 + r;
                int col = col0 + wc*64 + tj*16 + lm;
                float x = acc[ti][tj][r] + bias[col];
                float e = __expf(2.f*x);
                C[(size_t)row*D_ + col] = 1.f - 2.f/(e + 1.f);   // tanh
            }
}

// ===========================================================================
// Stage 5a: init output with bias
// ===========================================================================
__global__ void out_init(const float* __restrict__ bb, float* __restrict__ out)
{
    int i = blockIdx.x*256 + threadIdx.x;
    if (i < NROW*C_) out[i] = bb[i % C_];
}

// ===========================================================================
// Stage 5b helpers: direct-L2 B-frag load (R14-verified) + 4-rowtile compute.
// ===========================================================================
__device__ __forceinline__ void loadB_frag(const unsigned short* __restrict__ bbase,
                                           int i, s8 (&dst)[4][2])
{
    #pragma unroll
    for (int ct = 0; ct < 4; ++ct) {
        dst[ct][0] = *(const s8*)(bbase + (size_t)i*8192 + ct*1024);
        dst[ct][1] = *(const s8*)(bbase + (size_t)i*8192 + ct*1024 + 512);
    }
}

__device__ __forceinline__ void compute_i4(const s8 (&bfr)[4][2],
                                           const float (&sh)[4],
                                           const float (&tvv)[4][2][8],
                                           f4 (&acc)[4][4])
{
    // A-frags: bf16-truncate(hv_i * tv) packed via v_perm (R9-verified path),
    // now for 4 row-tiles sharing the same B fragments.
    s8 afr[4][2];
    #pragma unroll
    for (int rt = 0; rt < 4; ++rt)
        #pragma unroll
        for (int j2 = 0; j2 < 2; ++j2) {
            union { unsigned u[4]; s8 v; } cv;
            #pragma unroll
            for (int t2 = 0; t2 < 4; ++t2) {
                float pe = sh[rt] * tvv[rt][j2][t2*2];
                float po = sh[rt] * tvv[rt][j2][t2*2 + 1];
                cv.u[t2] = __builtin_amdgcn_perm(__builtin_bit_cast(unsigned, po),
                                                 __builtin_bit_cast(unsigned, pe),
                                                 0x07060302u);
            }
            afr[rt][j2] = cv.v;
        }
    #pragma unroll
    for (int ct = 0; ct < 4; ++ct)
        #pragma unroll
        for (int rt = 0; rt < 4; ++rt) {
            acc[rt][ct] = __builtin_amdgcn_mfma_f32_16x16x32_bf16(afr[rt][0], bfr[ct][0], acc[rt][ct], 0, 0, 0);
            acc[rt][ct] = __builtin_amdgcn_mfma_f32_16x16x32_bf16(afr[rt][1], bfr[ct][1], acc[rt][ct], 0, 0, 0);
        }
}

// ===========================================================================
// Stage 5b: block-bilinear classifier — R19: 128 ROWS PER BLOCK (rt=4).
// Ladder: R14 direct-L2 = 82-88us; R16 i-split (more blocks) FAILED (scheduler
// won't co-reside more blocks); R17/R18 sched_barrier pin FAILED (VGPR 92,
// occupancy crash, 100us). Remaining knob on the latency model
// (64 serial i-steps x exposed-latency x 3 sequential blocks/CU): amortize —
// each B-fragment now feeds 4 row-tiles (128 rows): blocks 768->384 (1.5
// sequential/CU), per-CU load-instr count and WbT L2 traffic HALVE, compute
// per latency step doubles (32 MFMA + 2x A-build ~ 500cy covers an L2 hit).
// Registers: acc 64 + tvv 64 + B-bank 32 + temps ~= 200-220 VGPR -> 2
// waves/SIMD = same residency as measured today, half the work chains.
// Falsifier: VGPR>=256 (spill) or dur>=82 -> revert to R14 exact.
// ===========================================================================
__global__ __launch_bounds__(256) void final_mfma(
    const float* __restrict__ hv,             // [4096][768] f32
    const float* __restrict__ tv,
    const unsigned short* __restrict__ WbT,   // [12][64][2][4][2][4][16][8] bf16
    float* __restrict__ out)                  // [4096][97] f32
{
    int kb   = blockIdx.x;
    int row0 = blockIdx.y * 128;
    __shared__ __attribute__((aligned(16))) unsigned short hS[128][72];
    __shared__ __attribute__((aligned(16))) unsigned short tS[128][72];

    int tid = threadIdx.x;
    // stage hv/tv kb-slices (128 rows x 64), f32 -> bf16 on the fly
    for (int e = tid; e < 2048; e += 256) {
        int r = e >> 4, part = e & 15;
        float4 xh = *(const float4*)(hv + (size_t)(row0 + r)*D_ + kb*BLK_ + part*4);
        float4 xt = *(const float4*)(tv + (size_t)(row0 + r)*D_ + kb*BLK_ + part*4);
        ushort4v ph = { f2bf(xh.x), f2bf(xh.y), f2bf(xh.z), f2bf(xh.w) };
        ushort4v pt = { f2bf(xt.x), f2bf(xt.y), f2bf(xt.z), f2bf(xt.w) };
        *(ushort4v*)&hS[r][part*4] = ph;
        *(ushort4v*)&tS[r][part*4] = pt;
    }
    int wave = tid >> 6, lane = tid & 63;
    int wr = wave & 1, wc = wave >> 1;
    int lm = lane & 15, quad = lane >> 4;
    __syncthreads();

    // preload tv fragments as scalar f32 (i-invariant within this kb), 4 row-tiles
    float tvv[4][2][8];   // [rowtile][jhalf][t]
    #pragma unroll
    for (int rt = 0; rt < 4; ++rt)
        #pragma unroll
        for (int j2 = 0; j2 < 2; ++j2) {
            int r = wr*64 + rt*16 + lm;
            ushort8 w = *(const ushort8*)&tS[r][j2*32 + quad*8];
            #pragma unroll
            for (int t = 0; t < 8; ++t) tvv[rt][j2][t] = bf2f(w[t]);
        }

    f4 acc[4][4] = {};
    // per-lane base into dense frag-packed WbT:
    // frag(i, ct, j2) at bbase + i*8192 + ct*1024 + j2*512  (bf16 units)
    const unsigned short* bbase = WbT + (size_t)kb*(64*128*64)
                                + (size_t)wc*4096 + ((size_t)quad*16 + lm)*8;

    // 2-deep register pipeline over i (plain form; R14-verified behavior)
    s8 bufA[4][2], bufB[4][2];
    loadB_frag(bbase, 0, bufA);
    for (int i0 = 0; i0 < 64; i0 += 2) {
        loadB_frag(bbase, i0 + 1, bufB);
        {
            float sh[4];
            #pragma unroll
            for (int rt = 0; rt < 4; ++rt) sh[rt] = bf2f(hS[wr*64 + rt*16 + lm][i0]);
            compute_i4(bufA, sh, tvv, acc);
        }
        if (i0 < 62) loadB_frag(bbase, i0 + 2, bufA);
        {
            float sh[4];
            #pragma unroll
            for (int rt = 0; rt < 4; ++rt) sh[rt] = bf2f(hS[wr*64 + rt*16 + lm][i0 + 1]);
            compute_i4(bufB, sh, tvv, acc);
        }
    }

    #pragma unroll
    for (int rt = 0; rt < 4; ++rt)
        #pragma unroll
        for (int ct = 0; ct < 4; ++ct)
            #pragma unroll
            for (int r = 0; r < 4; ++r) {
                int row = row0 + wr*64 + rt*16 + quad*4 + r;
                int col = wc*64 + ct*16 + lm;
                if (col < C_) atomicAdd(out + (size_t)row*C_ + col, acc[rt][ct][r]);
            }
}

// ===========================================================================
extern "C" void kernel_launch(void* const* d_in, const int* in_sizes, int n_in,
                              void* d_out, int out_size, void* d_ws, size_t ws_size,
                              hipStream_t stream)
{
    const float* seq_lhs = (const float*)d_in[0];
    const float* ent_lhs = (const float*)d_in[1];
    const float* attn    = (const float*)d_in[2];
    const int*   labels  = (const int*)d_in[3];
    const int*   hts     = (const int*)d_in[4];
    const float* Wh      = (const float*)d_in[5];
    const float* bh      = (const float*)d_in[6];
    const float* Wt      = (const float*)d_in[7];
    const float* bt      = (const float*)d_in[8];
    const float* Wb      = (const float*)d_in[9];
    const float* bb      = (const float*)d_in[10];
    float* out = (float*)d_out;

    float* wsf      = (float*)d_ws;
    float* hv       = wsf;                       // 3145728 f32
    float* tv       = hv + 3145728;              // 3145728 f32
    unsigned short* ent_embB  = (unsigned short*)(tv + 3145728); // 262144
    unsigned short* ent_attnB = ent_embB  + 262144;   // 2097152
    unsigned short* htA       = ent_attnB + 2097152;  // 2097152
    unsigned short* seqT      = htA       + 2097152;  // 2097152
    unsigned short* WhT       = seqT      + 2097152;  // 1572864
    unsigned short* WtT       = WhT       + 1572864;  // 1572864
    unsigned short* Ah        = WtT       + 1572864;  // 8388608 ([4096][2048])
    unsigned short* At        = Ah        + 8388608;  // 8388608
    unsigned short* WbT       = At        + 8388608;  // 6291456
    // total ~90.4 MB

    // weight preps (independent of activations)
    transpose_cvt_W<<<dim3(24, 64, 2), 256, 0, stream>>>(Wh, Wt, WhT, WtT);
    prep_WbT<<<KB_*64, 256, 0, stream>>>(Wb, WbT);
    transpose_cvt_seq<<<dim3(32, 16, B_), 256, 0, stream>>>(seq_lhs, seqT);

    pool_lse<<<B_*E_, 256, 0, stream>>>(ent_lhs, labels, ent_embB);
    pool_attn<<<dim3(E_, B_*NH_), 256, 0, stream>>>(attn, labels, ent_attnB);
    pair_attn_kernel<<<B_*R_/4, 256, 0, stream>>>(ent_attnB, hts, htA);
    gemm_rel_mfma<<<dim3(8, 8, B_), 256, 0, stream>>>(htA, seqT, Ah, At);
    prep_gather<<<NROW, 256, 0, stream>>>(ent_embB, hts, Ah, At);
    gemm_ext_mfma<<<dim3(6, 32, 2), 256, 0, stream>>>(Ah, At, WhT, WtT, bh, bt, hv, tv);
    out_init<<<(NROW*C_ + 255)/256, 256, 0, stream>>>(bb, out);
    final_mfma<<<dim3(KB_, NROW/128), 256, 0, stream>>>(hv, tv, WbT, out);
}

// Round 11
// 281.767 us; speedup vs baseline: 1.1143x; 1.0663x over previous
//
#include <hip/hip_runtime.h>
#include <hip/hip_bf16.h>
#include <math.h>

// Problem constants
#define B_  4
#define L_  512
#define H_  1024
#define M_  128
#define E_  64
#define NH_ 16
#define R_  1024
#define D_  768
#define BLK_ 64
#define C_  97
#define NROW (B_*R_)          // 4096
#define KB_  (D_/BLK_)        // 12

typedef __attribute__((ext_vector_type(8))) unsigned short ushort8;
typedef __attribute__((ext_vector_type(4))) unsigned short ushort4v;
typedef __attribute__((ext_vector_type(8))) short s8;       // 8 bf16 MFMA operand
typedef __attribute__((ext_vector_type(4))) float f4;       // MFMA C/D

__device__ __forceinline__ unsigned short f2bf(float x) {   // RNE f32->bf16
    unsigned u = __builtin_bit_cast(unsigned, x);
    unsigned r = (u + 0x7fffu + ((u >> 16) & 1u)) >> 16;
    return (unsigned short)r;
}
__device__ __forceinline__ float bf2f(unsigned short h) {
    unsigned u = ((unsigned)h) << 16;
    return __builtin_bit_cast(float, u);
}
__device__ __forceinline__ float lo16f(unsigned u) { return __builtin_bit_cast(float, u << 16); }
__device__ __forceinline__ float hi16f(unsigned u) { return __builtin_bit_cast(float, u & 0xffff0000u); }

// async global->LDS 16B (compiler never auto-emits; m97 lever). LDS dest
// semantics: wave-uniform base + lane*16 — callers must pass lane-linear lds.
__device__ __forceinline__ void gload_lds16(const unsigned short* g, unsigned short* l)
{
    __builtin_amdgcn_global_load_lds(
        (const __attribute__((address_space(1))) unsigned int*)g,
        (__attribute__((address_space(3))) unsigned int*)l, 16, 0, 0);
}

// ===========================================================================
// Stage 1a: entity logsumexp pooling -> bf16 (R9-verified)
// ===========================================================================
__global__ __launch_bounds__(256) void pool_lse(
    const float* __restrict__ ent_lhs, const int* __restrict__ labels,
    unsigned short* __restrict__ ent_embB)
{
    int be = blockIdx.x, b = be >> 6, e = be & 63;
    __shared__ int midx[M_];
    __shared__ int scnt;
    if (threadIdx.x == 0) scnt = 0;
    __syncthreads();
    if (threadIdx.x < M_) {
        if (labels[b*M_ + threadIdx.x] == e) {
            int p = atomicAdd(&scnt, 1);
            midx[p] = threadIdx.x;
        }
    }
    __syncthreads();
    int cnt = scnt;
    for (int h = threadIdx.x; h < H_; h += blockDim.x) {
        float r = 0.f;
        if (cnt > 0) {
            const float* base = ent_lhs + (size_t)b*M_*H_ + h;
            float mx = -INFINITY;
            for (int k = 0; k < cnt; ++k) mx = fmaxf(mx, base[(size_t)midx[k]*H_]);
            float s = 0.f;
            for (int k = 0; k < cnt; ++k) s += expf(base[(size_t)midx[k]*H_] - mx);
            r = mx + logf(s);
        }
        ent_embB[(size_t)be*H_ + h] = f2bf(r);
    }
}

// ===========================================================================
// Stage 1b: entity attention mean -> bf16. grid (E, B*NH)  (R9-verified)
// ===========================================================================
__global__ __launch_bounds__(256) void pool_attn(
    const float* __restrict__ attn, const int* __restrict__ labels,
    unsigned short* __restrict__ ent_attnB)
{
    int e  = blockIdx.x;
    int y  = blockIdx.y;          // b*NH + nh
    int b  = y >> 4, nh = y & 15;
    __shared__ int midx[M_];
    __shared__ int scnt;
    if (threadIdx.x == 0) scnt = 0;
    __syncthreads();
    if (threadIdx.x < M_) {
        if (labels[b*M_ + threadIdx.x] == e) {
            int p = atomicAdd(&scnt, 1);
            midx[p] = threadIdx.x;
        }
    }
    __syncthreads();
    int cnt = scnt;
    float inv = (cnt > 0) ? 1.f/(float)cnt : 0.f;
    const float* base = attn + ((size_t)(b*NH_ + nh)*M_)*L_;
    #pragma unroll
    for (int q = 0; q < 2; ++q) {
        int l = threadIdx.x + q*256;
        float s = 0.f;
        for (int k = 0; k < cnt; ++k) s += base[(size_t)midx[k]*L_ + l];
        ent_attnB[((size_t)(b*E_ + e)*NH_ + nh)*L_ + l] = f2bf(s * inv);
    }
}

// ===========================================================================
// Stage 2: pair attention — R18-verified WAVE-PER-PAIR (no LDS, no barrier).
// ===========================================================================
__global__ __launch_bounds__(256) void pair_attn_kernel(
    const unsigned short* __restrict__ entA, const int* __restrict__ hts,
    unsigned short* __restrict__ htA)
{
    int w  = threadIdx.x >> 6, ln = threadIdx.x & 63;
    int br = blockIdx.x*4 + w, b = br >> 10;
    int hi = hts[br*2 + 0], ti = hts[br*2 + 1];
    const unsigned* ph = (const unsigned*)(entA + ((size_t)(b*E_ + hi)*NH_)*L_);
    const unsigned* pt = (const unsigned*)(entA + ((size_t)(b*E_ + ti)*NH_)*L_);
    float v0[4] = {0.f, 0.f, 0.f, 0.f};
    float v1[4] = {0.f, 0.f, 0.f, 0.f};
    #pragma unroll
    for (int nh = 0; nh < NH_; ++nh) {
        #pragma unroll
        for (int c = 0; c < 4; ++c) {
            int l2 = ln + c*64;
            unsigned a = ph[nh*(L_/2) + l2], d = pt[nh*(L_/2) + l2];
            v0[c] += lo16f(a)*lo16f(d);
            v1[c] += hi16f(a)*hi16f(d);
        }
    }
    float part = 0.f;
    #pragma unroll
    for (int c = 0; c < 4; ++c) part += v0[c] + v1[c];
    #pragma unroll
    for (int off = 32; off > 0; off >>= 1) part += __shfl_xor(part, off, 64);
    float norm = 1.f / (part*(1.f/16.f) + 1e-5f);   // denom on sum of nh-means
    #pragma unroll
    for (int c = 0; c < 4; ++c) {
        unsigned short o0 = f2bf(v0[c]*(1.f/16.f)*norm);
        unsigned short o1 = f2bf(v1[c]*(1.f/16.f)*norm);
        *(unsigned*)(htA + (size_t)br*L_ + (size_t)(ln + c*64)*2) = ((unsigned)o1 << 16) | o0;
    }
}

// ===========================================================================
// Preps (R8-verified)
// ===========================================================================
__global__ __launch_bounds__(256) void transpose_cvt_seq(const float* __restrict__ in,
                                                         unsigned short* __restrict__ outp)
{
    int b = blockIdx.z;
    int h0 = blockIdx.x*32, l0 = blockIdx.y*32;
    __shared__ float tile[32][33];
    int tx = threadIdx.x & 31, ty = threadIdx.x >> 5;
    #pragma unroll
    for (int p = 0; p < 4; ++p)
        tile[ty + p*8][tx] = in[((size_t)b*L_ + l0 + ty + p*8)*H_ + h0 + tx];
    __syncthreads();
    #pragma unroll
    for (int p = 0; p < 4; ++p)
        outp[((size_t)b*H_ + h0 + ty + p*8)*L_ + l0 + tx] = f2bf(tile[tx][ty + p*8]);
}

__global__ __launch_bounds__(256) void transpose_cvt_W(const float* __restrict__ Wh,
                                                       const float* __restrict__ Wt,
                                                       unsigned short* __restrict__ WhT,
                                                       unsigned short* __restrict__ WtT)
{
    const float* in = blockIdx.z ? Wt : Wh;
    unsigned short* outp = blockIdx.z ? WtT : WhT;
    int n0 = blockIdx.x*32, k0 = blockIdx.y*32;
    __shared__ float tile[32][33];
    int tx = threadIdx.x & 31, ty = threadIdx.x >> 5;
    #pragma unroll
    for (int p = 0; p < 4; ++p)
        tile[ty + p*8][tx] = in[((size_t)(k0 + ty + p*8))*D_ + n0 + tx];
    __syncthreads();
    #pragma unroll
    for (int p = 0; p < 4; ++p) {
        int n = n0 + ty + p*8;
        outp[(size_t)n*2048 + k0 + tx] = f2bf(tile[tx][ty + p*8]);
    }
}

// WbT layout (R14): fragment-packed DENSE per wave-instruction.
// Element (i, c=wc*64+ct*16+lm, j=j2*32+quad*8+t) stored at
//   [kb][i][wc][ct][j2][quad][lm][t]
__global__ __launch_bounds__(256) void prep_WbT(const float* __restrict__ Wb,
                                                unsigned short* __restrict__ outp)
{
    int blk = blockIdx.x;                 // kb*64 + i
    __shared__ float sW[64*97];
    const float* src = Wb + (size_t)blk*64*97;
    for (int e = threadIdx.x; e < 64*97; e += 256) sW[e] = src[e];
    __syncthreads();
    unsigned short* dst = outp + (size_t)blk*128*64;
    for (int e = threadIdx.x; e < 128*64; e += 256) {
        int wcq = e >> 12;            // wc
        int ct  = (e >> 10) & 3;
        int j2  = (e >> 9) & 1;
        int qd  = (e >> 7) & 3;
        int lm  = (e >> 3) & 15;
        int t   = e & 7;
        int c   = wcq*64 + ct*16 + lm;
        int j   = j2*32 + qd*8 + t;   // k-index pairing preserved (R8 algebra)
        dst[e] = (c < C_) ? f2bf(sW[j*97 + c]) : (unsigned short)0;
    }
}

// ===========================================================================
// bf16 MFMA GEMM core — R15-verified async global_load_lds staging, R20:
// generalized with explicit lda/ldb strides (K-slices via base-ptr offsets;
// all offsets 16B-aligned). As/Bs UNPADDED [128][32], lds_byte = ch*16.
// ===========================================================================
__device__ __forceinline__ void gemm128_core(const unsigned short* __restrict__ A, int lda,
                                             const unsigned short* __restrict__ Bt, int ldb,
                                             int K, int row0, int col0,
                                             f4 (&acc)[4][4])
{
    __shared__ __attribute__((aligned(16))) unsigned short As[128][32];
    __shared__ __attribute__((aligned(16))) unsigned short Bs[128][32];
    int tid = threadIdx.x;
    int wave = tid >> 6, lane = tid & 63;
    int wr = wave & 1, wc = wave >> 1;
    int lm = lane & 15, quad = lane >> 4;

    for (int k0 = 0; k0 < K; k0 += 32) {
        #pragma unroll
        for (int s = 0; s < 2; ++s) {
            int ch = tid + s*256;
            int row = ch >> 2, part = ch & 3;     // lds_byte = ch*16 (lane-linear)
            gload_lds16(A  + (size_t)(row0 + row)*lda + k0 + part*8, &As[0][0] + ch*8);
            gload_lds16(Bt + (size_t)(col0 + row)*ldb + k0 + part*8, &Bs[0][0] + ch*8);
        }
        __syncthreads();   // compiler drains vmcnt(0) before s_barrier
        s8 a[4], b[4];
        #pragma unroll
        for (int ti = 0; ti < 4; ++ti) a[ti] = *(const s8*)&As[wr*64 + ti*16 + lm][quad*8];
        #pragma unroll
        for (int tj = 0; tj < 4; ++tj) b[tj] = *(const s8*)&Bs[wc*64 + tj*16 + lm][quad*8];
        #pragma unroll
        for (int ti = 0; ti < 4; ++ti)
            #pragma unroll
            for (int tj = 0; tj < 4; ++tj)
                acc[ti][tj] = __builtin_amdgcn_mfma_f32_16x16x32_bf16(a[ti], b[tj], acc[ti][tj], 0, 0, 0);
        __syncthreads();
    }
}

// ===========================================================================
// Stage 3: rel GEMM — R20: writes ONE relB [4096][1024] bf16 (was: two
// copies into Ah/At cols [1024,2048); the ent part is now handled by P).
// ===========================================================================
__global__ __launch_bounds__(256) void gemm_rel_mfma(const unsigned short* __restrict__ htA,
                                                     const unsigned short* __restrict__ seqT,
                                                     unsigned short* __restrict__ relB)
{
    int z = blockIdx.z;
    const unsigned short* A  = htA  + (size_t)z*R_*L_;
    const unsigned short* Bt = seqT + (size_t)z*H_*L_;
    int row0 = blockIdx.y*128, col0 = blockIdx.x*128;
    f4 acc[4][4] = {};
    gemm128_core(A, L_, Bt, L_, L_, row0, col0, acc);
    int lane = threadIdx.x & 63, wave = threadIdx.x >> 6;
    int wr = wave & 1, wc = wave >> 1, lm = lane & 15, quad = lane >> 4;
    #pragma unroll
    for (int ti = 0; ti < 4; ++ti)
        #pragma unroll
        for (int tj = 0; tj < 4; ++tj)
            #pragma unroll
            for (int r = 0; r < 4; ++r) {
                int n   = z*R_ + row0 + wr*64 + ti*16 + quad*4 + r;
                int col = col0 + wc*64 + tj*16 + lm;
                relB[(size_t)n*H_ + col] = f2bf(acc[ti][tj][r]);
            }
}

// ===========================================================================
// Stage 4a (R20): P GEMM — P_z = ent_emb . W_top  [256 x 768], K=1024,
// split-K x4 via f32 atomicAdd into bias-seeded P (out_init). Factoring:
// [hs|rel].W = gather(ent_emb.W_top, idx) + rel.W_bot — hs rows come from
// only B*E=256 distinct entities, so the old 4096-row K=2048 ext GEMM
// (25.8 GF) becomes P (0.8 GF) + Q (12.9 GF): 47% less work, and
// prep_gather + the Ah/At buffers are deleted.
// grid (6, 8, 2): y = mtile(2) | ksplit(4)<<1
// ===========================================================================
__global__ __launch_bounds__(256) void gemm_p_mfma(
    const unsigned short* __restrict__ ent_embB,
    const unsigned short* __restrict__ WhT, const unsigned short* __restrict__ WtT,
    float* __restrict__ Ph, float* __restrict__ Pt)
{
    int z = blockIdx.z;
    const unsigned short* Bt = z ? WtT : WhT;
    float* P = z ? Pt : Ph;
    int mt = blockIdx.y & 1, ks = blockIdx.y >> 1;
    int row0 = mt*128, col0 = blockIdx.x*128;
    f4 acc[4][4] = {};
    gemm128_core(ent_embB + ks*256, H_, Bt + ks*256, 2048, 256, row0, col0, acc);
    int lane = threadIdx.x & 63, wave = threadIdx.x >> 6;
    int wr = wave & 1, wc = wave >> 1, lm = lane & 15, quad = lane >> 4;
    #pragma unroll
    for (int ti = 0; ti < 4; ++ti)
        #pragma unroll
        for (int tj = 0; tj < 4; ++tj)
            #pragma unroll
            for (int r = 0; r < 4; ++r) {
                int row = row0 + wr*64 + ti*16 + quad*4 + r;
                int col = col0 + wc*64 + tj*16 + lm;
                atomicAdd(P + (size_t)row*D_ + col, acc[ti][tj][r]);
            }
}

// ===========================================================================
// Stage 4b (R20): Q GEMM — Q_z = rel . W_bot  [4096 x 768], K=1024.
// Epilogue: x = Q + P_z[b*E + hts[row][z]][col]  (P carries bias), tanh.
// P table is 0.75MB L2-resident; gather = 16-lane-contiguous 64B segments.
// ===========================================================================
__global__ __launch_bounds__(256) void gemm_ext_mfma(
    const unsigned short* __restrict__ relB,
    const unsigned short* __restrict__ WhT, const unsigned short* __restrict__ WtT,
    const float* __restrict__ Ph, const float* __restrict__ Pt,
    const int* __restrict__ hts,
    float* __restrict__ hv, float* __restrict__ tv)
{
    int z = blockIdx.z;
    const unsigned short* Bt = (z ? WtT : WhT) + 1024;   // W_bot k-slice
    const float* P = z ? Pt : Ph;
    float* Cv = z ? tv : hv;
    int row0 = blockIdx.y*128, col0 = blockIdx.x*128;
    f4 acc[4][4] = {};
    gemm128_core(relB, H_, Bt, 2048, H_, row0, col0, acc);
    int lane = threadIdx.x & 63, wave = threadIdx.x >> 6;
    int wr = wave & 1, wc = wave >> 1, lm = lane & 15, quad = lane >> 4;
    #pragma unroll
    for (int ti = 0; ti < 4; ++ti)
        #pragma unroll
        for (int r = 0; r < 4; ++r) {
            int row = row0 + wr*64 + ti*16 + quad*4 + r;
            int b   = row >> 10;
            int idx = hts[row*2 + z];
            const float* prow = P + ((size_t)(b*E_ + idx))*D_;
            #pragma unroll
            for (int tj = 0; tj < 4; ++tj) {
                int col = col0 + wc*64 + tj*16 + lm;
                float x = acc[ti][tj][r] + prow[col];
                float e = __expf(2.f*x);
                Cv[(size_t)row*D_ + col] = 1.f - 2.f/(e + 1.f);   // tanh
            }
        }
}

// ===========================================================================
// Stage 5a: init output with bias; seed P_h/P_t with bh/bt (R20)
// ===========================================================================
__global__ void out_init(const float* __restrict__ bb,
                         const float* __restrict__ bh, const float* __restrict__ bt,
                         float* __restrict__ out,
                         float* __restrict__ Ph, float* __restrict__ Pt)
{
    int i = blockIdx.x*256 + threadIdx.x;
    if (i < NROW*C_) out[i] = bb[i % C_];
    if (i < 256*D_) {
        Ph[i] = bh[i % D_];
        Pt[i] = bt[i % D_];
    }
}

// ===========================================================================
// Stage 5b helpers: direct-L2 B-frag load (R14-verified) + 4-rowtile compute.
// ===========================================================================
__device__ __forceinline__ void loadB_frag(const unsigned short* __restrict__ bbase,
                                           int i, s8 (&dst)[4][2])
{
    #pragma unroll
    for (int ct = 0; ct < 4; ++ct) {
        dst[ct][0] = *(const s8*)(bbase + (size_t)i*8192 + ct*1024);
        dst[ct][1] = *(const s8*)(bbase + (size_t)i*8192 + ct*1024 + 512);
    }
}

__device__ __forceinline__ void compute_i4(const s8 (&bfr)[4][2],
                                           const float (&sh)[4],
                                           const float (&tvv)[4][2][8],
                                           f4 (&acc)[4][4])
{
    s8 afr[4][2];
    #pragma unroll
    for (int rt = 0; rt < 4; ++rt)
        #pragma unroll
        for (int j2 = 0; j2 < 2; ++j2) {
            union { unsigned u[4]; s8 v; } cv;
            #pragma unroll
            for (int t2 = 0; t2 < 4; ++t2) {
                float pe = sh[rt] * tvv[rt][j2][t2*2];
                float po = sh[rt] * tvv[rt][j2][t2*2 + 1];
                cv.u[t2] = __builtin_amdgcn_perm(__builtin_bit_cast(unsigned, po),
                                                 __builtin_bit_cast(unsigned, pe),
                                                 0x07060302u);
            }
            afr[rt][j2] = cv.v;
        }
    #pragma unroll
    for (int ct = 0; ct < 4; ++ct)
        #pragma unroll
        for (int rt = 0; rt < 4; ++rt) {
            acc[rt][ct] = __builtin_amdgcn_mfma_f32_16x16x32_bf16(afr[rt][0], bfr[ct][0], acc[rt][ct], 0, 0, 0);
            acc[rt][ct] = __builtin_amdgcn_mfma_f32_16x16x32_bf16(afr[rt][1], bfr[ct][1], acc[rt][ct], 0, 0, 0);
        }
}

// ===========================================================================
// Stage 5b: block-bilinear classifier — R19-verified (84.3us stable):
// 128 rows/block (rt=4), direct-L2 dense frag-packed WbT, 2-deep pipeline.
// Declared at HIP floor (R16 occupancy / R17-18 sched-pin / R19 amortize all
// exhausted); UNCHANGED.
// ===========================================================================
__global__ __launch_bounds__(256) void final_mfma(
    const float* __restrict__ hv,             // [4096][768] f32
    const float* __restrict__ tv,
    const unsigned short* __restrict__ WbT,   // [12][64][2][4][2][4][16][8] bf16
    float* __restrict__ out)                  // [4096][97] f32
{
    int kb   = blockIdx.x;
    int row0 = blockIdx.y * 128;
    __shared__ __attribute__((aligned(16))) unsigned short hS[128][72];
    __shared__ __attribute__((aligned(16))) unsigned short tS[128][72];

    int tid = threadIdx.x;
    for (int e = tid; e < 2048; e += 256) {
        int r = e >> 4, part = e & 15;
        float4 xh = *(const float4*)(hv + (size_t)(row0 + r)*D_ + kb*BLK_ + part*4);
        float4 xt = *(const float4*)(tv + (size_t)(row0 + r)*D_ + kb*BLK_ + part*4);
        ushort4v ph = { f2bf(xh.x), f2bf(xh.y), f2bf(xh.z), f2bf(xh.w) };
        ushort4v pt = { f2bf(xt.x), f2bf(xt.y), f2bf(xt.z), f2bf(xt.w) };
        *(ushort4v*)&hS[r][part*4] = ph;
        *(ushort4v*)&tS[r][part*4] = pt;
    }
    int wave = tid >> 6, lane = tid & 63;
    int wr = wave & 1, wc = wave >> 1;
    int lm = lane & 15, quad = lane >> 4;
    __syncthreads();

    float tvv[4][2][8];   // [rowtile][jhalf][t]
    #pragma unroll
    for (int rt = 0; rt < 4; ++rt)
        #pragma unroll
        for (int j2 = 0; j2 < 2; ++j2) {
            int r = wr*64 + rt*16 + lm;
            ushort8 w = *(const ushort8*)&tS[r][j2*32 + quad*8];
            #pragma unroll
            for (int t = 0; t < 8; ++t) tvv[rt][j2][t] = bf2f(w[t]);
        }

    f4 acc[4][4] = {};
    const unsigned short* bbase = WbT + (size_t)kb*(64*128*64)
                                + (size_t)wc*4096 + ((size_t)quad*16 + lm)*8;

    s8 bufA[4][2], bufB[4][2];
    loadB_frag(bbase, 0, bufA);
    for (int i0 = 0; i0 < 64; i0 += 2) {
        loadB_frag(bbase, i0 + 1, bufB);
        {
            float sh[4];
            #pragma unroll
            for (int rt = 0; rt < 4; ++rt) sh[rt] = bf2f(hS[wr*64 + rt*16 + lm][i0]);
            compute_i4(bufA, sh, tvv, acc);
        }
        if (i0 < 62) loadB_frag(bbase, i0 + 2, bufA);
        {
            float sh[4];
            #pragma unroll
            for (int rt = 0; rt < 4; ++rt) sh[rt] = bf2f(hS[wr*64 + rt*16 + lm][i0 + 1]);
            compute_i4(bufB, sh, tvv, acc);
        }
    }

    #pragma unroll
    for (int rt = 0; rt < 4; ++rt)
        #pragma unroll
        for (int ct = 0; ct < 4; ++ct)
            #pragma unroll
            for (int r = 0; r < 4; ++r) {
                int row = row0 + wr*64 + rt*16 + quad*4 + r;
                int col = wc*64 + ct*16 + lm;
                if (col < C_) atomicAdd(out + (size_t)row*C_ + col, acc[rt][ct][r]);
            }
}

// ===========================================================================
extern "C" void kernel_launch(void* const* d_in, const int* in_sizes, int n_in,
                              void* d_out, int out_size, void* d_ws, size_t ws_size,
                              hipStream_t stream)
{
    const float* seq_lhs = (const float*)d_in[0];
    const float* ent_lhs = (const float*)d_in[1];
    const float* attn    = (const float*)d_in[2];
    const int*   labels  = (const int*)d_in[3];
    const int*   hts     = (const int*)d_in[4];
    const float* Wh      = (const float*)d_in[5];
    const float* bh      = (const float*)d_in[6];
    const float* Wt      = (const float*)d_in[7];
    const float* bt      = (const float*)d_in[8];
    const float* Wb      = (const float*)d_in[9];
    const float* bb      = (const float*)d_in[10];
    float* out = (float*)d_out;

    float* wsf      = (float*)d_ws;
    float* hv       = wsf;                       // 3145728 f32
    float* tv       = hv + 3145728;              // 3145728 f32
    float* Ph       = tv + 3145728;              // 196608 f32 (256x768)
    float* Pt       = Ph + 196608;               // 196608 f32
    unsigned short* ent_embB  = (unsigned short*)(Pt + 196608);  // 262144 bf16
    unsigned short* ent_attnB = ent_embB  + 262144;   // 2097152
    unsigned short* htA       = ent_attnB + 2097152;  // 2097152
    unsigned short* seqT      = htA       + 2097152;  // 2097152
    unsigned short* WhT       = seqT      + 2097152;  // 1572864
    unsigned short* WtT       = WhT       + 1572864;  // 1572864
    unsigned short* relB      = WtT       + 1572864;  // 4194304 ([4096][1024])
    unsigned short* WbT       = relB      + 4194304;  // 6291456
    // total ~66 MB

    // weight preps (independent of activations)
    transpose_cvt_W<<<dim3(24, 64, 2), 256, 0, stream>>>(Wh, Wt, WhT, WtT);
    prep_WbT<<<KB_*64, 256, 0, stream>>>(Wb, WbT);
    transpose_cvt_seq<<<dim3(32, 16, B_), 256, 0, stream>>>(seq_lhs, seqT);

    pool_lse<<<B_*E_, 256, 0, stream>>>(ent_lhs, labels, ent_embB);
    out_init<<<(NROW*C_ + 255)/256, 256, 0, stream>>>(bb, bh, bt, out, Ph, Pt);
    gemm_p_mfma<<<dim3(6, 8, 2), 256, 0, stream>>>(ent_embB, WhT, WtT, Ph, Pt);
    pool_attn<<<dim3(E_, B_*NH_), 256, 0, stream>>>(attn, labels, ent_attnB);
    pair_attn_kernel<<<B_*R_/4, 256, 0, stream>>>(ent_attnB, hts, htA);
    gemm_rel_mfma<<<dim3(8, 8, B_), 256, 0, stream>>>(htA, seqT, relB);
    gemm_ext_mfma<<<dim3(6, 32, 2), 256, 0, stream>>>(relB, WhT, WtT, Ph, Pt, hts, hv, tv);
    final_mfma<<<dim3(KB_, NROW/128), 256, 0, stream>>>(hv, tv, WbT, out);
}

// Round 12
// 280.310 us; speedup vs baseline: 1.1201x; 1.0052x over previous
//
#include <hip/hip_runtime.h>
#include <hip/hip_bf16.h>
#include <math.h>

// Problem constants
#define B_  4
#define L_  512
#define H_  1024
#define M_  128
#define E_  64
#define NH_ 16
#define R_  1024
#define D_  768
#define BLK_ 64
#define C_  97
#define NROW (B_*R_)          // 4096
#define KB_  (D_/BLK_)        // 12

typedef __attribute__((ext_vector_type(8))) unsigned short ushort8;
typedef __attribute__((ext_vector_type(4))) unsigned short ushort4v;
typedef __attribute__((ext_vector_type(8))) short s8;       // 8 bf16 MFMA operand
typedef __attribute__((ext_vector_type(4))) float f4;       // MFMA C/D

__device__ __forceinline__ unsigned short f2bf(float x) {   // RNE f32->bf16
    unsigned u = __builtin_bit_cast(unsigned, x);
    unsigned r = (u + 0x7fffu + ((u >> 16) & 1u)) >> 16;
    return (unsigned short)r;
}
__device__ __forceinline__ float bf2f(unsigned short h) {
    unsigned u = ((unsigned)h) << 16;
    return __builtin_bit_cast(float, u);
}
__device__ __forceinline__ float lo16f(unsigned u) { return __builtin_bit_cast(float, u << 16); }
__device__ __forceinline__ float hi16f(unsigned u) { return __builtin_bit_cast(float, u & 0xffff0000u); }

// async global->LDS 16B (compiler never auto-emits; m97 lever). LDS dest
// semantics: wave-uniform base + lane*16 — callers must pass lane-linear lds.
__device__ __forceinline__ void gload_lds16(const unsigned short* g, unsigned short* l)
{
    __builtin_amdgcn_global_load_lds(
        (const __attribute__((address_space(1))) unsigned int*)g,
        (__attribute__((address_space(3))) unsigned int*)l, 16, 0, 0);
}

// ===========================================================================
// Stage 1a: entity logsumexp pooling -> bf16 (R9-verified)
// ===========================================================================
__global__ __launch_bounds__(256) void pool_lse(
    const float* __restrict__ ent_lhs, const int* __restrict__ labels,
    unsigned short* __restrict__ ent_embB)
{
    int be = blockIdx.x, b = be >> 6, e = be & 63;
    __shared__ int midx[M_];
    __shared__ int scnt;
    if (threadIdx.x == 0) scnt = 0;
    __syncthreads();
    if (threadIdx.x < M_) {
        if (labels[b*M_ + threadIdx.x] == e) {
            int p = atomicAdd(&scnt, 1);
            midx[p] = threadIdx.x;
        }
    }
    __syncthreads();
    int cnt = scnt;
    for (int h = threadIdx.x; h < H_; h += blockDim.x) {
        float r = 0.f;
        if (cnt > 0) {
            const float* base = ent_lhs + (size_t)b*M_*H_ + h;
            float mx = -INFINITY;
            for (int k = 0; k < cnt; ++k) mx = fmaxf(mx, base[(size_t)midx[k]*H_]);
            float s = 0.f;
            for (int k = 0; k < cnt; ++k) s += expf(base[(size_t)midx[k]*H_] - mx);
            r = mx + logf(s);
        }
        ent_embB[(size_t)be*H_ + h] = f2bf(r);
    }
}

// ===========================================================================
// Stage 1b: entity attention mean -> bf16. grid (E, B*NH)  (R9-verified)
// ===========================================================================
__global__ __launch_bounds__(256) void pool_attn(
    const float* __restrict__ attn, const int* __restrict__ labels,
    unsigned short* __restrict__ ent_attnB)
{
    int e  = blockIdx.x;
    int y  = blockIdx.y;          // b*NH + nh
    int b  = y >> 4, nh = y & 15;
    __shared__ int midx[M_];
    __shared__ int scnt;
    if (threadIdx.x == 0) scnt = 0;
    __syncthreads();
    if (threadIdx.x < M_) {
        if (labels[b*M_ + threadIdx.x] == e) {
            int p = atomicAdd(&scnt, 1);
            midx[p] = threadIdx.x;
        }
    }
    __syncthreads();
    int cnt = scnt;
    float inv = (cnt > 0) ? 1.f/(float)cnt : 0.f;
    const float* base = attn + ((size_t)(b*NH_ + nh)*M_)*L_;
    #pragma unroll
    for (int q = 0; q < 2; ++q) {
        int l = threadIdx.x + q*256;
        float s = 0.f;
        for (int k = 0; k < cnt; ++k) s += base[(size_t)midx[k]*L_ + l];
        ent_attnB[((size_t)(b*E_ + e)*NH_ + nh)*L_ + l] = f2bf(s * inv);
    }
}

// ===========================================================================
// Stage 2: pair attention — R18-verified WAVE-PER-PAIR (no LDS, no barrier).
// ===========================================================================
__global__ __launch_bounds__(256) void pair_attn_kernel(
    const unsigned short* __restrict__ entA, const int* __restrict__ hts,
    unsigned short* __restrict__ htA)
{
    int w  = threadIdx.x >> 6, ln = threadIdx.x & 63;
    int br = blockIdx.x*4 + w, b = br >> 10;
    int hi = hts[br*2 + 0], ti = hts[br*2 + 1];
    const unsigned* ph = (const unsigned*)(entA + ((size_t)(b*E_ + hi)*NH_)*L_);
    const unsigned* pt = (const unsigned*)(entA + ((size_t)(b*E_ + ti)*NH_)*L_);
    float v0[4] = {0.f, 0.f, 0.f, 0.f};
    float v1[4] = {0.f, 0.f, 0.f, 0.f};
    #pragma unroll
    for (int nh = 0; nh < NH_; ++nh) {
        #pragma unroll
        for (int c = 0; c < 4; ++c) {
            int l2 = ln + c*64;
            unsigned a = ph[nh*(L_/2) + l2], d = pt[nh*(L_/2) + l2];
            v0[c] += lo16f(a)*lo16f(d);
            v1[c] += hi16f(a)*hi16f(d);
        }
    }
    float part = 0.f;
    #pragma unroll
    for (int c = 0; c < 4; ++c) part += v0[c] + v1[c];
    #pragma unroll
    for (int off = 32; off > 0; off >>= 1) part += __shfl_xor(part, off, 64);
    float norm = 1.f / (part*(1.f/16.f) + 1e-5f);   // denom on sum of nh-means
    #pragma unroll
    for (int c = 0; c < 4; ++c) {
        unsigned short o0 = f2bf(v0[c]*(1.f/16.f)*norm);
        unsigned short o1 = f2bf(v1[c]*(1.f/16.f)*norm);
        *(unsigned*)(htA + (size_t)br*L_ + (size_t)(ln + c*64)*2) = ((unsigned)o1 << 16) | o0;
    }
}

// ===========================================================================
// Preps
// ===========================================================================
// R21: seq transpose DELETED — the SWT factoring consumes seq in natural
// [b][l][h] layout, so this is a flat f32->bf16 convert (fully coalesced).
__global__ __launch_bounds__(256) void cvt_seq(const float* __restrict__ in,
                                               unsigned short* __restrict__ outp)
{
    size_t i = ((size_t)blockIdx.x*256 + threadIdx.x) * 8;
    float4 a = *(const float4*)(in + i);
    float4 b = *(const float4*)(in + i + 4);
    ushort8 o = { f2bf(a.x), f2bf(a.y), f2bf(a.z), f2bf(a.w),
                  f2bf(b.x), f2bf(b.y), f2bf(b.z), f2bf(b.w) };
    *(ushort8*)(outp + i) = o;
}

__global__ __launch_bounds__(256) void transpose_cvt_W(const float* __restrict__ Wh,
                                                       const float* __restrict__ Wt,
                                                       unsigned short* __restrict__ WhT,
                                                       unsigned short* __restrict__ WtT)
{
    const float* in = blockIdx.z ? Wt : Wh;
    unsigned short* outp = blockIdx.z ? WtT : WhT;
    int n0 = blockIdx.x*32, k0 = blockIdx.y*32;
    __shared__ float tile[32][33];
    int tx = threadIdx.x & 31, ty = threadIdx.x >> 5;
    #pragma unroll
    for (int p = 0; p < 4; ++p)
        tile[ty + p*8][tx] = in[((size_t)(k0 + ty + p*8))*D_ + n0 + tx];
    __syncthreads();
    #pragma unroll
    for (int p = 0; p < 4; ++p) {
        int n = n0 + ty + p*8;
        outp[(size_t)n*2048 + k0 + tx] = f2bf(tile[tx][ty + p*8]);
    }
}

// WbT layout (R14): fragment-packed DENSE per wave-instruction.
// Element (i, c=wc*64+ct*16+lm, j=j2*32+quad*8+t) stored at
//   [kb][i][wc][ct][j2][quad][lm][t]
__global__ __launch_bounds__(256) void prep_WbT(const float* __restrict__ Wb,
                                                unsigned short* __restrict__ outp)
{
    int blk = blockIdx.x;                 // kb*64 + i
    __shared__ float sW[64*97];
    const float* src = Wb + (size_t)blk*64*97;
    for (int e = threadIdx.x; e < 64*97; e += 256) sW[e] = src[e];
    __syncthreads();
    unsigned short* dst = outp + (size_t)blk*128*64;
    for (int e = threadIdx.x; e < 128*64; e += 256) {
        int wcq = e >> 12;            // wc
        int ct  = (e >> 10) & 3;
        int j2  = (e >> 9) & 1;
        int qd  = (e >> 7) & 3;
        int lm  = (e >> 3) & 15;
        int t   = e & 7;
        int c   = wcq*64 + ct*16 + lm;
        int j   = j2*32 + qd*8 + t;   // k-index pairing preserved (R8 algebra)
        dst[e] = (c < C_) ? f2bf(sW[j*97 + c]) : (unsigned short)0;
    }
}

// ===========================================================================
// bf16 MFMA GEMM core — R15-verified async global_load_lds staging, R20:
// explicit lda/ldb strides (K-slices via base-ptr offsets; 16B-aligned).
// ===========================================================================
__device__ __forceinline__ void gemm128_core(const unsigned short* __restrict__ A, int lda,
                                             const unsigned short* __restrict__ Bt, int ldb,
                                             int K, int row0, int col0,
                                             f4 (&acc)[4][4])
{
    __shared__ __attribute__((aligned(16))) unsigned short As[128][32];
    __shared__ __attribute__((aligned(16))) unsigned short Bs[128][32];
    int tid = threadIdx.x;
    int wave = tid >> 6, lane = tid & 63;
    int wr = wave & 1, wc = wave >> 1;
    int lm = lane & 15, quad = lane >> 4;

    for (int k0 = 0; k0 < K; k0 += 32) {
        #pragma unroll
        for (int s = 0; s < 2; ++s) {
            int ch = tid + s*256;
            int row = ch >> 2, part = ch & 3;     // lds_byte = ch*16 (lane-linear)
            gload_lds16(A  + (size_t)(row0 + row)*lda + k0 + part*8, &As[0][0] + ch*8);
            gload_lds16(Bt + (size_t)(col0 + row)*ldb + k0 + part*8, &Bs[0][0] + ch*8);
        }
        __syncthreads();   // compiler drains vmcnt(0) before s_barrier
        s8 a[4], b[4];
        #pragma unroll
        for (int ti = 0; ti < 4; ++ti) a[ti] = *(const s8*)&As[wr*64 + ti*16 + lm][quad*8];
        #pragma unroll
        for (int tj = 0; tj < 4; ++tj) b[tj] = *(const s8*)&Bs[wc*64 + tj*16 + lm][quad*8];
        #pragma unroll
        for (int ti = 0; ti < 4; ++ti)
            #pragma unroll
            for (int tj = 0; tj < 4; ++tj)
                acc[ti][tj] = __builtin_amdgcn_mfma_f32_16x16x32_bf16(a[ti], b[tj], acc[ti][tj], 0, 0, 0);
        __syncthreads();
    }
}

// ===========================================================================
// Stage 3 (R21): SWT GEMM — SWT_z[b] = W_bot^T . seq_b^T  [768 x 512].
// Associativity: Q = (htA.seq^T).W_bot = htA.(seq.W_bot); computing
// SWT[d][l] = sum_h Wbot[h][d].seq[b][l][h] directly gives a row-major
// coalesced C-write (A = WhT rows d with k-offset 1024; Bt = seqB natural).
// Replaces gemm_rel (4.3 GF) + relB 16MB roundtrip: chain 17.2 -> 12.9 GF.
// grid (4, 6, 8): x = l-tile, y = d-tile, z = (z<<2)|b
// ===========================================================================
__global__ __launch_bounds__(256) void gemm_swt_mfma(
    const unsigned short* __restrict__ seqB,
    const unsigned short* __restrict__ WhT, const unsigned short* __restrict__ WtT,
    unsigned short* __restrict__ SWT)
{
    int bz = blockIdx.z, z = bz >> 2, b = bz & 3;
    const unsigned short* A  = (z ? WtT : WhT) + 1024;     // W_bot: rows d, k-offset
    const unsigned short* Bt = seqB + (size_t)b*L_*H_;     // rows l, k = h
    int row0 = blockIdx.y*128, col0 = blockIdx.x*128;
    f4 acc[4][4] = {};
    gemm128_core(A, 2048, Bt, H_, H_, row0, col0, acc);
    unsigned short* Cb = SWT + ((size_t)(z*B_ + b)*D_)*L_;
    int lane = threadIdx.x & 63, wave = threadIdx.x >> 6;
    int wr = wave & 1, wc = wave >> 1, lm = lane & 15, quad = lane >> 4;
    #pragma unroll
    for (int ti = 0; ti < 4; ++ti)
        #pragma unroll
        for (int tj = 0; tj < 4; ++tj)
            #pragma unroll
            for (int r = 0; r < 4; ++r) {
                int d = row0 + wr*64 + ti*16 + quad*4 + r;
                int l = col0 + wc*64 + tj*16 + lm;
                Cb[(size_t)d*L_ + l] = f2bf(acc[ti][tj][r]);
            }
}

// ===========================================================================
// Stage 4a (R20-verified): P GEMM — P_z = ent_emb . W_top  [256 x 768],
// K=1024, split-K x4 via f32 atomicAdd into bias-seeded P.
// grid (6, 8, 2): y = mtile(2) | ksplit(4)<<1
// ===========================================================================
__global__ __launch_bounds__(256) void gemm_p_mfma(
    const unsigned short* __restrict__ ent_embB,
    const unsigned short* __restrict__ WhT, const unsigned short* __restrict__ WtT,
    float* __restrict__ Ph, float* __restrict__ Pt)
{
    int z = blockIdx.z;
    const unsigned short* Bt = z ? WtT : WhT;
    float* P = z ? Pt : Ph;
    int mt = blockIdx.y & 1, ks = blockIdx.y >> 1;
    int row0 = mt*128, col0 = blockIdx.x*128;
    f4 acc[4][4] = {};
    gemm128_core(ent_embB + ks*256, H_, Bt + ks*256, 2048, 256, row0, col0, acc);
    int lane = threadIdx.x & 63, wave = threadIdx.x >> 6;
    int wr = wave & 1, wc = wave >> 1, lm = lane & 15, quad = lane >> 4;
    #pragma unroll
    for (int ti = 0; ti < 4; ++ti)
        #pragma unroll
        for (int tj = 0; tj < 4; ++tj)
            #pragma unroll
            for (int r = 0; r < 4; ++r) {
                int row = row0 + wr*64 + ti*16 + quad*4 + r;
                int col = col0 + wc*64 + tj*16 + lm;
                atomicAdd(P + (size_t)row*D_ + col, acc[ti][tj][r]);
            }
}

// ===========================================================================
// Stage 4b (R21): Q GEMM — Q_z = htA . SWT_z  [4096 x 768], K=512.
// Epilogue: x = Q + P_z[b*E + hts[row][z]][col] (P carries bias), tanh,
// and hv/tv are written as BF16 (the f2bf final_mfma's staging did anyway):
// ext write 24->12 MB, final FETCH 24.6->12.6 MB, staging = pure copy.
// ===========================================================================
__global__ __launch_bounds__(256) void gemm_ext_mfma(
    const unsigned short* __restrict__ htA,
    const unsigned short* __restrict__ SWT,
    const float* __restrict__ Ph, const float* __restrict__ Pt,
    const int* __restrict__ hts,
    unsigned short* __restrict__ hvB, unsigned short* __restrict__ tvB)
{
    int z = blockIdx.z;
    const float* P = z ? Pt : Ph;
    unsigned short* Cv = z ? tvB : hvB;
    int row0 = blockIdx.y*128, col0 = blockIdx.x*128;
    int b = row0 >> 10;                               // 128-row tiles don't cross b
    const unsigned short* Bt = SWT + ((size_t)(z*B_ + b)*D_)*L_;
    f4 acc[4][4] = {};
    gemm128_core(htA, L_, Bt, L_, L_, row0, col0, acc);
    int lane = threadIdx.x & 63, wave = threadIdx.x >> 6;
    int wr = wave & 1, wc = wave >> 1, lm = lane & 15, quad = lane >> 4;
    #pragma unroll
    for (int ti = 0; ti < 4; ++ti)
        #pragma unroll
        for (int r = 0; r < 4; ++r) {
            int row = row0 + wr*64 + ti*16 + quad*4 + r;
            int idx = hts[row*2 + z];
            const float* prow = P + ((size_t)(b*E_ + idx))*D_;
            #pragma unroll
            for (int tj = 0; tj < 4; ++tj) {
                int col = col0 + wc*64 + tj*16 + lm;
                float x = acc[ti][tj][r] + prow[col];
                float e = __expf(2.f*x);
                Cv[(size_t)row*D_ + col] = f2bf(1.f - 2.f/(e + 1.f));   // tanh
            }
        }
}

// ===========================================================================
// Stage 5a: init output with bias; seed P_h/P_t with bh/bt (R20)
// ===========================================================================
__global__ void out_init(const float* __restrict__ bb,
                         const float* __restrict__ bh, const float* __restrict__ bt,
                         float* __restrict__ out,
                         float* __restrict__ Ph, float* __restrict__ Pt)
{
    int i = blockIdx.x*256 + threadIdx.x;
    if (i < NROW*C_) out[i] = bb[i % C_];
    if (i < 256*D_) {
        Ph[i] = bh[i % D_];
        Pt[i] = bt[i % D_];
    }
}

// ===========================================================================
// Stage 5b helpers: direct-L2 B-frag load (R14-verified) + 4-rowtile compute.
// ===========================================================================
__device__ __forceinline__ void loadB_frag(const unsigned short* __restrict__ bbase,
                                           int i, s8 (&dst)[4][2])
{
    #pragma unroll
    for (int ct = 0; ct < 4; ++ct) {
        dst[ct][0] = *(const s8*)(bbase + (size_t)i*8192 + ct*1024);
        dst[ct][1] = *(const s8*)(bbase + (size_t)i*8192 + ct*1024 + 512);
    }
}

__device__ __forceinline__ void compute_i4(const s8 (&bfr)[4][2],
                                           const float (&sh)[4],
                                           const float (&tvv)[4][2][8],
                                           f4 (&acc)[4][4])
{
    s8 afr[4][2];
    #pragma unroll
    for (int rt = 0; rt < 4; ++rt)
        #pragma unroll
        for (int j2 = 0; j2 < 2; ++j2) {
            union { unsigned u[4]; s8 v; } cv;
            #pragma unroll
            for (int t2 = 0; t2 < 4; ++t2) {
                float pe = sh[rt] * tvv[rt][j2][t2*2];
                float po = sh[rt] * tvv[rt][j2][t2*2 + 1];
                cv.u[t2] = __builtin_amdgcn_perm(__builtin_bit_cast(unsigned, po),
                                                 __builtin_bit_cast(unsigned, pe),
                                                 0x07060302u);
            }
            afr[rt][j2] = cv.v;
        }
    #pragma unroll
    for (int ct = 0; ct < 4; ++ct)
        #pragma unroll
        for (int rt = 0; rt < 4; ++rt) {
            acc[rt][ct] = __builtin_amdgcn_mfma_f32_16x16x32_bf16(afr[rt][0], bfr[ct][0], acc[rt][ct], 0, 0, 0);
            acc[rt][ct] = __builtin_amdgcn_mfma_f32_16x16x32_bf16(afr[rt][1], bfr[ct][1], acc[rt][ct], 0, 0, 0);
        }
}

// ===========================================================================
// Stage 5b: block-bilinear classifier — R19-verified structure (84.3us
// stable, declared HIP floor). R21 delta: hv/tv arrive as BF16, so staging
// is a pure ushort8 copy (no f2bf) and FETCH halves. Numerics identical.
// ===========================================================================
__global__ __launch_bounds__(256) void final_mfma(
    const unsigned short* __restrict__ hvB,   // [4096][768] bf16
    const unsigned short* __restrict__ tvB,
    const unsigned short* __restrict__ WbT,   // [12][64][2][4][2][4][16][8] bf16
    float* __restrict__ out)                  // [4096][97] f32
{
    int kb   = blockIdx.x;
    int row0 = blockIdx.y * 128;
    __shared__ __attribute__((aligned(16))) unsigned short hS[128][72];
    __shared__ __attribute__((aligned(16))) unsigned short tS[128][72];

    int tid = threadIdx.x;
    for (int e = tid; e < 1024; e += 256) {
        int r = e >> 3, part = e & 7;
        *(ushort8*)&hS[r][part*8] = *(const ushort8*)(hvB + (size_t)(row0 + r)*D_ + kb*BLK_ + part*8);
        *(ushort8*)&tS[r][part*8] = *(const ushort8*)(tvB + (size_t)(row0 + r)*D_ + kb*BLK_ + part*8);
    }
    int wave = tid >> 6, lane = tid & 63;
    int wr = wave & 1, wc = wave >> 1;
    int lm = lane & 15, quad = lane >> 4;
    __syncthreads();

    float tvv[4][2][8];   // [rowtile][jhalf][t]
    #pragma unroll
    for (int rt = 0; rt < 4; ++rt)
        #pragma unroll
        for (int j2 = 0; j2 < 2; ++j2) {
            int r = wr*64 + rt*16 + lm;
            ushort8 w = *(const ushort8*)&tS[r][j2*32 + quad*8];
            #pragma unroll
            for (int t = 0; t < 8; ++t) tvv[rt][j2][t] = bf2f(w[t]);
        }

    f4 acc[4][4] = {};
    const unsigned short* bbase = WbT + (size_t)kb*(64*128*64)
                                + (size_t)wc*4096 + ((size_t)quad*16 + lm)*8;

    s8 bufA[4][2], bufB[4][2];
    loadB_frag(bbase, 0, bufA);
    for (int i0 = 0; i0 < 64; i0 += 2) {
        loadB_frag(bbase, i0 + 1, bufB);
        {
            float sh[4];
            #pragma unroll
            for (int rt = 0; rt < 4; ++rt) sh[rt] = bf2f(hS[wr*64 + rt*16 + lm][i0]);
            compute_i4(bufA, sh, tvv, acc);
        }
        if (i0 < 62) loadB_frag(bbase, i0 + 2, bufA);
        {
            float sh[4];
            #pragma unroll
            for (int rt = 0; rt < 4; ++rt) sh[rt] = bf2f(hS[wr*64 + rt*16 + lm][i0 + 1]);
            compute_i4(bufB, sh, tvv, acc);
        }
    }

    #pragma unroll
    for (int rt = 0; rt < 4; ++rt)
        #pragma unroll
        for (int ct = 0; ct < 4; ++ct)
            #pragma unroll
            for (int r = 0; r < 4; ++r) {
                int row = row0 + wr*64 + rt*16 + quad*4 + r;
                int col = wc*64 + ct*16 + lm;
                if (col < C_) atomicAdd(out + (size_t)row*C_ + col, acc[rt][ct][r]);
            }
}

// ===========================================================================
extern "C" void kernel_launch(void* const* d_in, const int* in_sizes, int n_in,
                              void* d_out, int out_size, void* d_ws, size_t ws_size,
                              hipStream_t stream)
{
    const float* seq_lhs = (const float*)d_in[0];
    const float* ent_lhs = (const float*)d_in[1];
    const float* attn    = (const float*)d_in[2];
    const int*   labels  = (const int*)d_in[3];
    const int*   hts     = (const int*)d_in[4];
    const float* Wh      = (const float*)d_in[5];
    const float* bh      = (const float*)d_in[6];
    const float* Wt      = (const float*)d_in[7];
    const float* bt      = (const float*)d_in[8];
    const float* Wb      = (const float*)d_in[9];
    const float* bb      = (const float*)d_in[10];
    float* out = (float*)d_out;

    float* wsf      = (float*)d_ws;
    float* Ph       = wsf;                            // 196608 f32 (256x768)
    float* Pt       = Ph + 196608;                    // 196608 f32
    unsigned short* hvB       = (unsigned short*)(Pt + 196608);  // 3145728 bf16
    unsigned short* tvB       = hvB       + 3145728;  // 3145728
    unsigned short* ent_embB  = tvB       + 3145728;  // 262144
    unsigned short* ent_attnB = ent_embB  + 262144;   // 2097152
    unsigned short* htA       = ent_attnB + 2097152;  // 2097152
    unsigned short* seqB      = htA       + 2097152;  // 2097152 ([b][l][h])
    unsigned short* WhT       = seqB      + 2097152;  // 1572864
    unsigned short* WtT       = WhT       + 1572864;  // 1572864
    unsigned short* SWT       = WtT       + 1572864;  // 3145728 ([z][b][768][512])
    unsigned short* WbT       = SWT       + 3145728;  // 6291456
    // total ~53 MB

    // weight preps (independent of activations)
    transpose_cvt_W<<<dim3(24, 64, 2), 256, 0, stream>>>(Wh, Wt, WhT, WtT);
    prep_WbT<<<KB_*64, 256, 0, stream>>>(Wb, WbT);
    cvt_seq<<<1024, 256, 0, stream>>>(seq_lhs, seqB);

    pool_lse<<<B_*E_, 256, 0, stream>>>(ent_lhs, labels, ent_embB);
    out_init<<<(NROW*C_ + 255)/256, 256, 0, stream>>>(bb, bh, bt, out, Ph, Pt);
    gemm_p_mfma<<<dim3(6, 8, 2), 256, 0, stream>>>(ent_embB, WhT, WtT, Ph, Pt);
    gemm_swt_mfma<<<dim3(4, 6, 8), 256, 0, stream>>>(seqB, WhT, WtT, SWT);
    pool_attn<<<dim3(E_, B_*NH_), 256, 0, stream>>>(attn, labels, ent_attnB);
    pair_attn_kernel<<<B_*R_/4, 256, 0, stream>>>(ent_attnB, hts, htA);
    gemm_ext_mfma<<<dim3(6, 32, 2), 256, 0, stream>>>(htA, SWT, Ph, Pt, hts, hvB, tvB);
    final_mfma<<<dim3(KB_, NROW/128), 256, 0, stream>>>(hvB, tvB, WbT, out);
}

// Round 13
// 244.330 us; speedup vs baseline: 1.2851x; 1.1473x over previous
//
#include <hip/hip_runtime.h>
#include <hip/hip_bf16.h>
#include <math.h>

// Problem constants
#define B_  4
#define L_  512
#define H_  1024
#define M_  128
#define E_  64
#define NH_ 16
#define R_  1024
#define D_  768
#define BLK_ 64
#define C_  97
#define NROW (B_*R_)          // 4096
#define KB_  (D_/BLK_)        // 12

typedef __attribute__((ext_vector_type(8))) unsigned short ushort8;
typedef __attribute__((ext_vector_type(4))) unsigned short ushort4v;
typedef __attribute__((ext_vector_type(8))) short s8;       // 8 bf16 MFMA operand
typedef __attribute__((ext_vector_type(4))) float f4;       // MFMA C/D

__device__ __forceinline__ unsigned short f2bf(float x) {   // RNE f32->bf16
    unsigned u = __builtin_bit_cast(unsigned, x);
    unsigned r = (u + 0x7fffu + ((u >> 16) & 1u)) >> 16;
    return (unsigned short)r;
}
__device__ __forceinline__ float bf2f(unsigned short h) {
    unsigned u = ((unsigned)h) << 16;
    return __builtin_bit_cast(float, u);
}
__device__ __forceinline__ float lo16f(unsigned u) { return __builtin_bit_cast(float, u << 16); }
__device__ __forceinline__ float hi16f(unsigned u) { return __builtin_bit_cast(float, u & 0xffff0000u); }

// async global->LDS 16B (compiler never auto-emits; m97 lever). LDS dest
// semantics: wave-uniform base + lane*16 — callers must pass lane-linear lds.
__device__ __forceinline__ void gload_lds16(const unsigned short* g, unsigned short* l)
{
    __builtin_amdgcn_global_load_lds(
        (const __attribute__((address_space(1))) unsigned int*)g,
        (__attribute__((address_space(3))) unsigned int*)l, 16, 0, 0);
}

// ===========================================================================
// R22: LAUNCH FUSION. R11/R12 evidence: others-bucket barely responds to
// work removal (R0 217us -> R12 195us despite deleting prep_gather, halving
// ext, removing rel GEMM). Roofline sum of all non-final kernels ~65-75us;
// the ~120us gap over 10 serial kernel boundaries ~= 12us/boundary of
// launch/drain overhead. Fix: 11 launches -> 4 via blockIdx-dispatch
// mega-kernels over INDEPENDENT sub-kernels (verbatim bodies, re-indexed):
//   fused_prep: cvt_W | prep_WbT | cvt_seq | pool_lse | pool_attn | out_init
//   fused_mid : gemm_p | gemm_swt | pair_attn
//   gemm_ext, final_mfma: unchanged (sequential deps).
// ===========================================================================

// ---------------------------------------------------------------------------
// fused_prep — grid.x partitions:
// [0,3072) cvt_W | [3072,3840) prep_WbT | [3840,4864) cvt_seq |
// [4864,5120) pool_lse | [5120,9216) pool_attn | [9216,10768) out_init
// ---------------------------------------------------------------------------
__global__ __launch_bounds__(256) void fused_prep(
    const float* __restrict__ Wh, const float* __restrict__ Wt,
    unsigned short* __restrict__ WhT, unsigned short* __restrict__ WtT,
    const float* __restrict__ Wb, unsigned short* __restrict__ WbT,
    const float* __restrict__ seq_lhs, unsigned short* __restrict__ seqB,
    const float* __restrict__ ent_lhs, const int* __restrict__ labels,
    unsigned short* __restrict__ ent_embB,
    const float* __restrict__ attn, unsigned short* __restrict__ ent_attnB,
    const float* __restrict__ bb, const float* __restrict__ bh,
    const float* __restrict__ bt,
    float* __restrict__ out, float* __restrict__ Ph, float* __restrict__ Pt)
{
    __shared__ __attribute__((aligned(16))) float smem[6208];   // 24832 B scratch
    int bx = blockIdx.x, tid = threadIdx.x;

    if (bx < 3072) {
        // ---- transpose_cvt_W (verbatim; z = bx/1536, ky = (bx%1536)/24, kx = %24)
        int z = bx / 1536, rem = bx % 1536;
        int ky = rem / 24, kx = rem % 24;
        const float* in = z ? Wt : Wh;
        unsigned short* outp = z ? WtT : WhT;
        int n0 = kx*32, k0 = ky*32;
        float (*tile)[33] = (float(*)[33])smem;
        int tx = tid & 31, ty = tid >> 5;
        #pragma unroll
        for (int p = 0; p < 4; ++p)
            tile[ty + p*8][tx] = in[((size_t)(k0 + ty + p*8))*D_ + n0 + tx];
        __syncthreads();
        #pragma unroll
        for (int p = 0; p < 4; ++p) {
            int n = n0 + ty + p*8;
            outp[(size_t)n*2048 + k0 + tx] = f2bf(tile[tx][ty + p*8]);
        }
    } else if (bx < 3840) {
        // ---- prep_WbT (verbatim; R14 frag-packed dense layout)
        int blk = bx - 3072;                 // kb*64 + i
        float* sW = smem;                    // 64*97
        const float* src = Wb + (size_t)blk*64*97;
        for (int e = tid; e < 64*97; e += 256) sW[e] = src[e];
        __syncthreads();
        unsigned short* dst = WbT + (size_t)blk*128*64;
        for (int e = tid; e < 128*64; e += 256) {
            int wcq = e >> 12;
            int ct  = (e >> 10) & 3;
            int j2  = (e >> 9) & 1;
            int qd  = (e >> 7) & 3;
            int lm  = (e >> 3) & 15;
            int t   = e & 7;
            int c   = wcq*64 + ct*16 + lm;
            int j   = j2*32 + qd*8 + t;
            dst[e] = (c < C_) ? f2bf(sW[j*97 + c]) : (unsigned short)0;
        }
    } else if (bx < 4864) {
        // ---- cvt_seq (verbatim)
        size_t i = ((size_t)(bx - 3840)*256 + tid) * 8;
        float4 a = *(const float4*)(seq_lhs + i);
        float4 b = *(const float4*)(seq_lhs + i + 4);
        ushort8 o = { f2bf(a.x), f2bf(a.y), f2bf(a.z), f2bf(a.w),
                      f2bf(b.x), f2bf(b.y), f2bf(b.z), f2bf(b.w) };
        *(ushort8*)(seqB + i) = o;
    } else if (bx < 5120) {
        // ---- pool_lse (verbatim)
        int be = bx - 4864, b = be >> 6, e = be & 63;
        int* midx = (int*)smem;
        int* scnt = (int*)smem + M_;
        if (tid == 0) *scnt = 0;
        __syncthreads();
        if (tid < M_) {
            if (labels[b*M_ + tid] == e) {
                int p = atomicAdd(scnt, 1);
                midx[p] = tid;
            }
        }
        __syncthreads();
        int cnt = *scnt;
        for (int h = tid; h < H_; h += 256) {
            float r = 0.f;
            if (cnt > 0) {
                const float* base = ent_lhs + (size_t)b*M_*H_ + h;
                float mx = -INFINITY;
                for (int k = 0; k < cnt; ++k) mx = fmaxf(mx, base[(size_t)midx[k]*H_]);
                float s = 0.f;
                for (int k = 0; k < cnt; ++k) s += expf(base[(size_t)midx[k]*H_] - mx);
                r = mx + logf(s);
            }
            ent_embB[(size_t)be*H_ + h] = f2bf(r);
        }
    } else if (bx < 9216) {
        // ---- pool_attn (verbatim; id = bx-5120, e = id&63, y = id>>6)
        int id = bx - 5120;
        int e = id & 63, y = id >> 6;
        int b = y >> 4, nh = y & 15;
        int* midx = (int*)smem;
        int* scnt = (int*)smem + M_;
        if (tid == 0) *scnt = 0;
        __syncthreads();
        if (tid < M_) {
            if (labels[b*M_ + tid] == e) {
                int p = atomicAdd(scnt, 1);
                midx[p] = tid;
            }
        }
        __syncthreads();
        int cnt = *scnt;
        float inv = (cnt > 0) ? 1.f/(float)cnt : 0.f;
        const float* base = attn + ((size_t)(b*NH_ + nh)*M_)*L_;
        #pragma unroll
        for (int q = 0; q < 2; ++q) {
            int l = tid + q*256;
            float s = 0.f;
            for (int k = 0; k < cnt; ++k) s += base[(size_t)midx[k]*L_ + l];
            ent_attnB[((size_t)(b*E_ + e)*NH_ + nh)*L_ + l] = f2bf(s * inv);
        }
    } else {
        // ---- out_init (verbatim)
        int i = (bx - 9216)*256 + tid;
        if (i < NROW*C_) out[i] = bb[i % C_];
        if (i < 256*D_) {
            Ph[i] = bh[i % D_];
            Pt[i] = bt[i % D_];
        }
    }
}

// ===========================================================================
// bf16 MFMA GEMM core — R15-verified async global_load_lds staging, R20:
// explicit lda/ldb strides (K-slices via base-ptr offsets; 16B-aligned).
// ===========================================================================
__device__ __forceinline__ void gemm128_core(const unsigned short* __restrict__ A, int lda,
                                             const unsigned short* __restrict__ Bt, int ldb,
                                             int K, int row0, int col0,
                                             f4 (&acc)[4][4])
{
    __shared__ __attribute__((aligned(16))) unsigned short As[128][32];
    __shared__ __attribute__((aligned(16))) unsigned short Bs[128][32];
    int tid = threadIdx.x;
    int wave = tid >> 6, lane = tid & 63;
    int wr = wave & 1, wc = wave >> 1;
    int lm = lane & 15, quad = lane >> 4;

    for (int k0 = 0; k0 < K; k0 += 32) {
        #pragma unroll
        for (int s = 0; s < 2; ++s) {
            int ch = tid + s*256;
            int row = ch >> 2, part = ch & 3;     // lds_byte = ch*16 (lane-linear)
            gload_lds16(A  + (size_t)(row0 + row)*lda + k0 + part*8, &As[0][0] + ch*8);
            gload_lds16(Bt + (size_t)(col0 + row)*ldb + k0 + part*8, &Bs[0][0] + ch*8);
        }
        __syncthreads();   // compiler drains vmcnt(0) before s_barrier
        s8 a[4], b[4];
        #pragma unroll
        for (int ti = 0; ti < 4; ++ti) a[ti] = *(const s8*)&As[wr*64 + ti*16 + lm][quad*8];
        #pragma unroll
        for (int tj = 0; tj < 4; ++tj) b[tj] = *(const s8*)&Bs[wc*64 + tj*16 + lm][quad*8];
        #pragma unroll
        for (int ti = 0; ti < 4; ++ti)
            #pragma unroll
            for (int tj = 0; tj < 4; ++tj)
                acc[ti][tj] = __builtin_amdgcn_mfma_f32_16x16x32_bf16(a[ti], b[tj], acc[ti][tj], 0, 0, 0);
        __syncthreads();
    }
}

// ---------------------------------------------------------------------------
// fused_mid — grid.x partitions:
// [0,96) gemm_p | [96,288) gemm_swt | [288,1312) pair_attn
// ---------------------------------------------------------------------------
__global__ __launch_bounds__(256) void fused_mid(
    const unsigned short* __restrict__ ent_embB,
    const unsigned short* __restrict__ WhT, const unsigned short* __restrict__ WtT,
    float* __restrict__ Ph, float* __restrict__ Pt,
    const unsigned short* __restrict__ seqB, unsigned short* __restrict__ SWT,
    const unsigned short* __restrict__ entA, const int* __restrict__ hts,
    unsigned short* __restrict__ htA)
{
    int bx = blockIdx.x;
    if (bx < 96) {
        // ---- gemm_p (verbatim; x=bx%6, y=(bx/6)%8, z=bx/48)
        int x = bx % 6, y = (bx / 6) % 8, z = bx / 48;
        const unsigned short* Bt = z ? WtT : WhT;
        float* P = z ? Pt : Ph;
        int mt = y & 1, ks = y >> 1;
        int row0 = mt*128, col0 = x*128;
        f4 acc[4][4] = {};
        gemm128_core(ent_embB + ks*256, H_, Bt + ks*256, 2048, 256, row0, col0, acc);
        int lane = threadIdx.x & 63, wave = threadIdx.x >> 6;
        int wr = wave & 1, wc = wave >> 1, lm = lane & 15, quad = lane >> 4;
        #pragma unroll
        for (int ti = 0; ti < 4; ++ti)
            #pragma unroll
            for (int tj = 0; tj < 4; ++tj)
                #pragma unroll
                for (int r = 0; r < 4; ++r) {
                    int row = row0 + wr*64 + ti*16 + quad*4 + r;
                    int col = col0 + wc*64 + tj*16 + lm;
                    atomicAdd(P + (size_t)row*D_ + col, acc[ti][tj][r]);
                }
    } else if (bx < 288) {
        // ---- gemm_swt (verbatim; id=bx-96: x=id%4, y=(id/4)%6, z=id/24)
        int id = bx - 96;
        int x = id % 4, y = (id / 4) % 6, bz = id / 24;
        int z = bz >> 2, b = bz & 3;
        const unsigned short* A  = (z ? WtT : WhT) + 1024;
        const unsigned short* Bt = seqB + (size_t)b*L_*H_;
        int row0 = y*128, col0 = x*128;
        f4 acc[4][4] = {};
        gemm128_core(A, 2048, Bt, H_, H_, row0, col0, acc);
        unsigned short* Cb = SWT + ((size_t)(z*B_ + b)*D_)*L_;
        int lane = threadIdx.x & 63, wave = threadIdx.x >> 6;
        int wr = wave & 1, wc = wave >> 1, lm = lane & 15, quad = lane >> 4;
        #pragma unroll
        for (int ti = 0; ti < 4; ++ti)
            #pragma unroll
            for (int tj = 0; tj < 4; ++tj)
                #pragma unroll
                for (int r = 0; r < 4; ++r) {
                    int d = row0 + wr*64 + ti*16 + quad*4 + r;
                    int l = col0 + wc*64 + tj*16 + lm;
                    Cb[(size_t)d*L_ + l] = f2bf(acc[ti][tj][r]);
                }
    } else {
        // ---- pair_attn (R18-verified wave-per-pair, verbatim; id = bx-288)
        int id = bx - 288;
        int w  = threadIdx.x >> 6, ln = threadIdx.x & 63;
        int br = id*4 + w, b = br >> 10;
        int hi = hts[br*2 + 0], ti = hts[br*2 + 1];
        const unsigned* ph = (const unsigned*)(entA + ((size_t)(b*E_ + hi)*NH_)*L_);
        const unsigned* pt = (const unsigned*)(entA + ((size_t)(b*E_ + ti)*NH_)*L_);
        float v0[4] = {0.f, 0.f, 0.f, 0.f};
        float v1[4] = {0.f, 0.f, 0.f, 0.f};
        #pragma unroll
        for (int nh = 0; nh < NH_; ++nh) {
            #pragma unroll
            for (int c = 0; c < 4; ++c) {
                int l2 = ln + c*64;
                unsigned a = ph[nh*(L_/2) + l2], d = pt[nh*(L_/2) + l2];
                v0[c] += lo16f(a)*lo16f(d);
                v1[c] += hi16f(a)*hi16f(d);
            }
        }
        float part = 0.f;
        #pragma unroll
        for (int c = 0; c < 4; ++c) part += v0[c] + v1[c];
        #pragma unroll
        for (int off = 32; off > 0; off >>= 1) part += __shfl_xor(part, off, 64);
        float norm = 1.f / (part*(1.f/16.f) + 1e-5f);
        #pragma unroll
        for (int c = 0; c < 4; ++c) {
            unsigned short o0 = f2bf(v0[c]*(1.f/16.f)*norm);
            unsigned short o1 = f2bf(v1[c]*(1.f/16.f)*norm);
            *(unsigned*)(htA + (size_t)br*L_ + (size_t)(ln + c*64)*2) = ((unsigned)o1 << 16) | o0;
        }
    }
}

// ===========================================================================
// Stage 4b (R21-verified): Q GEMM — Q_z = htA . SWT_z  [4096 x 768], K=512.
// Epilogue: x = Q + P_z[gather] (P carries bias), tanh, bf16 out.
// ===========================================================================
__global__ __launch_bounds__(256) void gemm_ext_mfma(
    const unsigned short* __restrict__ htA,
    const unsigned short* __restrict__ SWT,
    const float* __restrict__ Ph, const float* __restrict__ Pt,
    const int* __restrict__ hts,
    unsigned short* __restrict__ hvB, unsigned short* __restrict__ tvB)
{
    int z = blockIdx.z;
    const float* P = z ? Pt : Ph;
    unsigned short* Cv = z ? tvB : hvB;
    int row0 = blockIdx.y*128, col0 = blockIdx.x*128;
    int b = row0 >> 10;                               // 128-row tiles don't cross b
    const unsigned short* Bt = SWT + ((size_t)(z*B_ + b)*D_)*L_;
    f4 acc[4][4] = {};
    gemm128_core(htA, L_, Bt, L_, L_, row0, col0, acc);
    int lane = threadIdx.x & 63, wave = threadIdx.x >> 6;
    int wr = wave & 1, wc = wave >> 1, lm = lane & 15, quad = lane >> 4;
    #pragma unroll
    for (int ti = 0; ti < 4; ++ti)
        #pragma unroll
        for (int r = 0; r < 4; ++r) {
            int row = row0 + wr*64 + ti*16 + quad*4 + r;
            int idx = hts[row*2 + z];
            const float* prow = P + ((size_t)(b*E_ + idx))*D_;
            #pragma unroll
            for (int tj = 0; tj < 4; ++tj) {
                int col = col0 + wc*64 + tj*16 + lm;
                float x = acc[ti][tj][r] + prow[col];
                float e = __expf(2.f*x);
                Cv[(size_t)row*D_ + col] = f2bf(1.f - 2.f/(e + 1.f));   // tanh
            }
        }
}

// ===========================================================================
// Stage 5b helpers: direct-L2 B-frag load (R14-verified) + 4-rowtile compute.
// ===========================================================================
__device__ __forceinline__ void loadB_frag(const unsigned short* __restrict__ bbase,
                                           int i, s8 (&dst)[4][2])
{
    #pragma unroll
    for (int ct = 0; ct < 4; ++ct) {
        dst[ct][0] = *(const s8*)(bbase + (size_t)i*8192 + ct*1024);
        dst[ct][1] = *(const s8*)(bbase + (size_t)i*8192 + ct*1024 + 512);
    }
}

__device__ __forceinline__ void compute_i4(const s8 (&bfr)[4][2],
                                           const float (&sh)[4],
                                           const float (&tvv)[4][2][8],
                                           f4 (&acc)[4][4])
{
    s8 afr[4][2];
    #pragma unroll
    for (int rt = 0; rt < 4; ++rt)
        #pragma unroll
        for (int j2 = 0; j2 < 2; ++j2) {
            union { unsigned u[4]; s8 v; } cv;
            #pragma unroll
            for (int t2 = 0; t2 < 4; ++t2) {
                float pe = sh[rt] * tvv[rt][j2][t2*2];
                float po = sh[rt] * tvv[rt][j2][t2*2 + 1];
                cv.u[t2] = __builtin_amdgcn_perm(__builtin_bit_cast(unsigned, po),
                                                 __builtin_bit_cast(unsigned, pe),
                                                 0x07060302u);
            }
            afr[rt][j2] = cv.v;
        }
    #pragma unroll
    for (int ct = 0; ct < 4; ++ct)
        #pragma unroll
        for (int rt = 0; rt < 4; ++rt) {
            acc[rt][ct] = __builtin_amdgcn_mfma_f32_16x16x32_bf16(afr[rt][0], bfr[ct][0], acc[rt][ct], 0, 0, 0);
            acc[rt][ct] = __builtin_amdgcn_mfma_f32_16x16x32_bf16(afr[rt][1], bfr[ct][1], acc[rt][ct], 0, 0, 0);
        }
}

// ===========================================================================
// Stage 5b: block-bilinear classifier — R19-verified structure (84-85us,
// declared HIP floor). hv/tv arrive as BF16 (R21); staging = pure copy.
// UNCHANGED.
// ===========================================================================
__global__ __launch_bounds__(256) void final_mfma(
    const unsigned short* __restrict__ hvB,   // [4096][768] bf16
    const unsigned short* __restrict__ tvB,
    const unsigned short* __restrict__ WbT,   // [12][64][2][4][2][4][16][8] bf16
    float* __restrict__ out)                  // [4096][97] f32
{
    int kb   = blockIdx.x;
    int row0 = blockIdx.y * 128;
    __shared__ __attribute__((aligned(16))) unsigned short hS[128][72];
    __shared__ __attribute__((aligned(16))) unsigned short tS[128][72];

    int tid = threadIdx.x;
    for (int e = tid; e < 1024; e += 256) {
        int r = e >> 3, part = e & 7;
        *(ushort8*)&hS[r][part*8] = *(const ushort8*)(hvB + (size_t)(row0 + r)*D_ + kb*BLK_ + part*8);
        *(ushort8*)&tS[r][part*8] = *(const ushort8*)(tvB + (size_t)(row0 + r)*D_ + kb*BLK_ + part*8);
    }
    int wave = tid >> 6, lane = tid & 63;
    int wr = wave & 1, wc = wave >> 1;
    int lm = lane & 15, quad = lane >> 4;
    __syncthreads();

    float tvv[4][2][8];   // [rowtile][jhalf][t]
    #pragma unroll
    for (int rt = 0; rt < 4; ++rt)
        #pragma unroll
        for (int j2 = 0; j2 < 2; ++j2) {
            int r = wr*64 + rt*16 + lm;
            ushort8 w = *(const ushort8*)&tS[r][j2*32 + quad*8];
            #pragma unroll
            for (int t = 0; t < 8; ++t) tvv[rt][j2][t] = bf2f(w[t]);
        }

    f4 acc[4][4] = {};
    const unsigned short* bbase = WbT + (size_t)kb*(64*128*64)
                                + (size_t)wc*4096 + ((size_t)quad*16 + lm)*8;

    s8 bufA[4][2], bufB[4][2];
    loadB_frag(bbase, 0, bufA);
    for (int i0 = 0; i0 < 64; i0 += 2) {
        loadB_frag(bbase, i0 + 1, bufB);
        {
            float sh[4];
            #pragma unroll
            for (int rt = 0; rt < 4; ++rt) sh[rt] = bf2f(hS[wr*64 + rt*16 + lm][i0]);
            compute_i4(bufA, sh, tvv, acc);
        }
        if (i0 < 62) loadB_frag(bbase, i0 + 2, bufA);
        {
            float sh[4];
            #pragma unroll
            for (int rt = 0; rt < 4; ++rt) sh[rt] = bf2f(hS[wr*64 + rt*16 + lm][i0 + 1]);
            compute_i4(bufB, sh, tvv, acc);
        }
    }

    #pragma unroll
    for (int rt = 0; rt < 4; ++rt)
        #pragma unroll
        for (int ct = 0; ct < 4; ++ct)
            #pragma unroll
            for (int r = 0; r < 4; ++r) {
                int row = row0 + wr*64 + rt*16 + quad*4 + r;
                int col = wc*64 + ct*16 + lm;
                if (col < C_) atomicAdd(out + (size_t)row*C_ + col, acc[rt][ct][r]);
            }
}

// ===========================================================================
extern "C" void kernel_launch(void* const* d_in, const int* in_sizes, int n_in,
                              void* d_out, int out_size, void* d_ws, size_t ws_size,
                              hipStream_t stream)
{
    const float* seq_lhs = (const float*)d_in[0];
    const float* ent_lhs = (const float*)d_in[1];
    const float* attn    = (const float*)d_in[2];
    const int*   labels  = (const int*)d_in[3];
    const int*   hts     = (const int*)d_in[4];
    const float* Wh      = (const float*)d_in[5];
    const float* bh      = (const float*)d_in[6];
    const float* Wt      = (const float*)d_in[7];
    const float* bt      = (const float*)d_in[8];
    const float* Wb      = (const float*)d_in[9];
    const float* bb      = (const float*)d_in[10];
    float* out = (float*)d_out;

    float* wsf      = (float*)d_ws;
    float* Ph       = wsf;                            // 196608 f32 (256x768)
    float* Pt       = Ph + 196608;                    // 196608 f32
    unsigned short* hvB       = (unsigned short*)(Pt + 196608);  // 3145728 bf16
    unsigned short* tvB       = hvB       + 3145728;  // 3145728
    unsigned short* ent_embB  = tvB       + 3145728;  // 262144
    unsigned short* ent_attnB = ent_embB  + 262144;   // 2097152
    unsigned short* htA       = ent_attnB + 2097152;  // 2097152
    unsigned short* seqB      = htA       + 2097152;  // 2097152 ([b][l][h])
    unsigned short* WhT       = seqB      + 2097152;  // 1572864
    unsigned short* WtT       = WhT       + 1572864;  // 1572864
    unsigned short* SWT       = WtT       + 1572864;  // 3145728 ([z][b][768][512])
    unsigned short* WbT       = SWT       + 3145728;  // 6291456
    // total ~53 MB

    fused_prep<<<10768, 256, 0, stream>>>(Wh, Wt, WhT, WtT, Wb, WbT,
                                          seq_lhs, seqB, ent_lhs, labels, ent_embB,
                                          attn, ent_attnB, bb, bh, bt, out, Ph, Pt);
    fused_mid<<<1312, 256, 0, stream>>>(ent_embB, WhT, WtT, Ph, Pt,
                                        seqB, SWT, ent_attnB, hts, htA);
    gemm_ext_mfma<<<dim3(6, 32, 2), 256, 0, stream>>>(htA, SWT, Ph, Pt, hts, hvB, tvB);
    final_mfma<<<dim3(KB_, NROW/128), 256, 0, stream>>>(hvB, tvB, WbT, out);
}